// Round 1
// baseline (3663.675 us; speedup 1.0000x reference)
//
#include <hip/hip_runtime.h>
#include <cstdint>
#include <cstddef>

#define NQ 40000
#define EDIM 128
#define NVAL 43520
#define NHEADS 8
#define HDIM 16
#define NLEV 4
#define NPTS 8
#define NCLS 21

// ---------------- mask ----------------
__global__ void reduce_max_int(const int* __restrict__ idx, int* __restrict__ mx) {
    int i = blockIdx.x * 256 + threadIdx.x;
    int v = (i < NQ) ? idx[i] : 0;  // values are >= 0
    for (int o = 32; o > 0; o >>= 1) v = max(v, __shfl_xor(v, o, 64));
    if ((threadIdx.x & 63) == 0) atomicMax(mx, v);
}

__global__ void write_mask(const int* __restrict__ idx, const int* __restrict__ mx,
                           float* __restrict__ out) {
    int i = blockIdx.x * 256 + threadIdx.x;
    if (i >= NQ) return;
    out[i] = (idx[i] < *mx) ? 1.0f : 0.0f;
}

// ---------------- elementwise add (qp = q + pos) ----------------
__global__ void add2_k(const float* __restrict__ a, const float* __restrict__ b,
                       float* __restrict__ c, int n) {
    int i = blockIdx.x * 256 + threadIdx.x;
    if (i < n) c[i] = a[i] + b[i];
}

// ---------------- GEMM: C[M][N] = A[M][128] @ W[128][N] + bias, optional relu ----------------
__global__ __launch_bounds__(256) void gemm_bias_k(
        const float* __restrict__ A, const float* __restrict__ W,
        const float* __restrict__ bias, float* __restrict__ C,
        int M, int N, int relu) {
    __shared__ float As[64][68];  // [k][m]
    __shared__ float Bs[64][68];  // [k][n]
    const int m0 = blockIdx.x * 64;
    const int n0 = blockIdx.y * 64;
    const int t  = threadIdx.x;
    const int tm = t >> 4, tn = t & 15;
    const int lr = t >> 4;          // 0..15
    const int lc = (t & 15) * 4;    // 0..60
    float acc[4][4] = {};
    for (int kc = 0; kc < 128; kc += 64) {
#pragma unroll
        for (int i = 0; i < 4; i++) {
            int r = i * 16 + lr;
            int gm = m0 + r;
            float4 av;
            if (gm < M) av = *(const float4*)(A + (size_t)gm * 128 + kc + lc);
            else av = make_float4(0.f, 0.f, 0.f, 0.f);
            As[lc + 0][r] = av.x;
            As[lc + 1][r] = av.y;
            As[lc + 2][r] = av.z;
            As[lc + 3][r] = av.w;
            float4 bv = *(const float4*)(W + (size_t)(kc + r) * N + n0 + lc);
            *(float4*)(&Bs[r][lc]) = bv;
        }
        __syncthreads();
#pragma unroll
        for (int k = 0; k < 64; k++) {
            float a4[4], b4[4];
            *(float4*)a4 = *(const float4*)(&As[k][tm * 4]);
            *(float4*)b4 = *(const float4*)(&Bs[k][tn * 4]);
#pragma unroll
            for (int i = 0; i < 4; i++)
#pragma unroll
                for (int j = 0; j < 4; j++)
                    acc[i][j] += a4[i] * b4[j];
        }
        __syncthreads();
    }
#pragma unroll
    for (int i = 0; i < 4; i++) {
        int gm = m0 + tm * 4 + i;
        if (gm >= M) continue;
#pragma unroll
        for (int j = 0; j < 4; j++) {
            int gn = n0 + tn * 4 + j;
            float v = acc[i][j] + bias[gn];
            if (relu) v = fmaxf(v, 0.f);
            C[(size_t)gm * N + gn] = v;
        }
    }
}

// ---------------- deformable sampling (softmax fused) ----------------
// off: [nq_chunk][512], logits: [nq_chunk][256], v: [NVAL][128], out: [NQ][128]
__global__ __launch_bounds__(256) void deform_sample_k(
        const float* __restrict__ v, const float* __restrict__ off,
        const float* __restrict__ logits, float* __restrict__ out,
        int q0, int nq) {
    const int t = threadIdx.x;
    const int sub = t >> 7;        // 0..1
    const int h = (t >> 4) & 7;    // head
    const int d = t & 15;          // hd lane
    const int qi = blockIdx.x * 2 + sub;   // chunk-local
    if (qi >= nq) return;
    const int gq = q0 + qi;
    const float rx = ((gq % 200) + 0.5f) / 200.f;
    const float ry = ((gq / 200) + 0.5f) / 200.f;
    const float* offp = off + (size_t)qi * 512 + h * 64;     // [lvl][pt][2]
    const float* logp = logits + (size_t)qi * 256 + h * 32;
    float lg[32];
    float mx = -1e30f;
#pragma unroll
    for (int i = 0; i < 32; i++) { lg[i] = logp[i]; mx = fmaxf(mx, lg[i]); }
    float ssum = 0.f;
#pragma unroll
    for (int i = 0; i < 32; i++) { lg[i] = __expf(lg[i] - mx); ssum += lg[i]; }
    const float inv = 1.f / ssum;

    const int HS[4] = {128, 64, 32, 16};
    const int WS[4] = {256, 128, 64, 32};
    const int ST[4] = {0, 32768, 40960, 43008};
    float acc = 0.f;
#pragma unroll
    for (int l = 0; l < 4; l++) {
        const int H = HS[l], W = WS[l], start = ST[l];
        const float fW = (float)W, fH = (float)H;
#pragma unroll
        for (int p = 0; p < 8; p++) {
            float ox = offp[(l * 8 + p) * 2 + 0];
            float oy = offp[(l * 8 + p) * 2 + 1];
            float x = rx * fW + ox - 0.5f;
            float y = ry * fH + oy - 0.5f;
            float x0 = floorf(x), y0 = floorf(y);
            float aw = lg[l * 8 + p] * inv;
#pragma unroll
            for (int cy = 0; cy < 2; cy++) {
#pragma unroll
                for (int cx = 0; cx < 2; cx++) {
                    float xc = x0 + cx, yc = y0 + cy;
                    float wgt = (1.f - fabsf(x - xc)) * (1.f - fabsf(y - yc));
                    bool valid = (xc >= 0.f) && (xc < fW) && (yc >= 0.f) && (yc < fH);
                    int xi = min(max((int)xc, 0), W - 1);
                    int yi = min(max((int)yc, 0), H - 1);
                    float val = v[(size_t)(start + yi * W + xi) * 128 + h * 16 + d];
                    acc += valid ? (aw * wgt * val) : 0.f;
                }
            }
        }
    }
    out[(size_t)gq * 128 + h * 16 + d] = acc;
}

// ---------------- fused residual + layernorm (in-place on q) ----------------
__global__ __launch_bounds__(256) void add_ln_k(
        float* __restrict__ q, const float* __restrict__ a,
        const float* __restrict__ g, const float* __restrict__ b) {
    const int row = blockIdx.x * 4 + (threadIdx.x >> 6);
    const int lane = threadIdx.x & 63;
    float s0 = q[(size_t)row * 128 + lane] + a[(size_t)row * 128 + lane];
    float s1 = q[(size_t)row * 128 + 64 + lane] + a[(size_t)row * 128 + 64 + lane];
    float sum = s0 + s1;
    for (int o = 32; o > 0; o >>= 1) sum += __shfl_xor(sum, o, 64);
    float mean = sum * (1.f / 128.f);
    float d0 = s0 - mean, d1 = s1 - mean;
    float vs = d0 * d0 + d1 * d1;
    for (int o = 32; o > 0; o >>= 1) vs += __shfl_xor(vs, o, 64);
    float inv = rsqrtf(vs * (1.f / 128.f) + 1e-5f);
    q[(size_t)row * 128 + lane]      = d0 * inv * g[lane] + b[lane];
    q[(size_t)row * 128 + 64 + lane] = d1 * inv * g[64 + lane] + b[64 + lane];
}

// ---------------- transpose q[40000][128] -> mem[128][40000] ----------------
__global__ void transpose_qc_k(const float* __restrict__ src, float* __restrict__ dst) {
    __shared__ float tile[32][33];
    int p0 = blockIdx.x * 32, c0 = blockIdx.y * 32;
    int tx = threadIdx.x & 31, ty = threadIdx.x >> 5;  // 32x8
    for (int i = 0; i < 32; i += 8)
        tile[ty + i][tx] = src[(size_t)(p0 + ty + i) * 128 + c0 + tx];
    __syncthreads();
    for (int i = 0; i < 32; i += 8)
        dst[(size_t)(c0 + ty + i) * 40000 + p0 + tx] = tile[tx][ty + i];
}

// ---------------- weight repack [OC][IC][K][K] -> [IC][K][K][OC] ----------------
__global__ void repack_w_k(const float* __restrict__ w, float* __restrict__ wT,
                           int OC, int IC, int KS) {
    int i = blockIdx.x * 256 + threadIdx.x;
    int tot = OC * IC * KS * KS;
    if (i >= tot) return;
    int kx = i % KS; int t1 = i / KS;
    int ky = t1 % KS; int t2 = t1 / KS;
    int ic = t2 % IC; int oc = t2 / IC;
    wT[((size_t)(ic * KS + ky) * KS + kx) * OC + oc] = w[i];
}

// ---------------- direct conv (16x16 pixel tile, 16 oc per block) ----------------
template <int KS, int PAD, int ICB>
__global__ __launch_bounds__(256) void conv_k(
        const float* __restrict__ in, const float* __restrict__ wT,
        float* __restrict__ out, int IC, int OC) {
    constexpr int TS = 16 + KS - 1;
    __shared__ float tile[ICB * TS * TS];
    const int x0 = blockIdx.x * 16, y0 = blockIdx.y * 16;
    const int oc0 = blockIdx.z * 16;
    const int tx = threadIdx.x & 15, ty = threadIdx.x >> 4;
    float acc[16] = {};
    for (int ic0 = 0; ic0 < IC; ic0 += ICB) {
        for (int i = threadIdx.x; i < ICB * TS * TS; i += 256) {
            int ic = i / (TS * TS); int r = i - ic * (TS * TS);
            int ly = r / TS, lx = r - ly * TS;
            int gy = y0 + ly - PAD, gx = x0 + lx - PAD;
            float v = 0.f;
            if (gy >= 0 && gy < 200 && gx >= 0 && gx < 200)
                v = in[(size_t)(ic0 + ic) * 40000 + gy * 200 + gx];
            tile[i] = v;
        }
        __syncthreads();
        for (int ic = 0; ic < ICB; ic++) {
#pragma unroll
            for (int ky = 0; ky < KS; ky++) {
#pragma unroll
                for (int kx = 0; kx < KS; kx++) {
                    float iv = tile[(ic * TS + ty + ky) * TS + tx + kx];
                    const float* wr = wT + ((size_t)((ic0 + ic) * KS + ky) * KS + kx) * OC + oc0;
#pragma unroll
                    for (int j = 0; j < 16; j++) acc[j] += iv * wr[j];
                }
            }
        }
        __syncthreads();
    }
    int x = x0 + tx, y = y0 + ty;
    if (x < 200 && y < 200) {
#pragma unroll
        for (int j = 0; j < 16; j++)
            out[(size_t)(oc0 + j) * 40000 + y * 200 + x] = acc[j];
    }
}

// ---------------- BN stats + apply ----------------
__global__ void bn_stats_k(const float* __restrict__ x, float* __restrict__ mv) {
    int c = blockIdx.x;
    const float* p = x + (size_t)c * 40000;
    float s = 0.f, s2 = 0.f;
    for (int i = threadIdx.x; i < 40000; i += 256) { float v = p[i]; s += v; s2 += v * v; }
    __shared__ float rs[256], rq[256];
    rs[threadIdx.x] = s; rq[threadIdx.x] = s2;
    __syncthreads();
    for (int o = 128; o > 0; o >>= 1) {
        if (threadIdx.x < o) { rs[threadIdx.x] += rs[threadIdx.x + o]; rq[threadIdx.x] += rq[threadIdx.x + o]; }
        __syncthreads();
    }
    if (threadIdx.x == 0) {
        float m = rs[0] / 40000.f;
        float var = rq[0] / 40000.f - m * m;
        mv[2 * c] = m;
        mv[2 * c + 1] = rsqrtf(var + 1e-5f);
    }
}

__global__ void bn_apply_k(float* __restrict__ x, const float* __restrict__ mv,
                           const float* __restrict__ g, const float* __restrict__ b) {
    int p = blockIdx.x * 256 + threadIdx.x;
    int c = blockIdx.y;
    if (p >= 40000) return;
    float m = mv[2 * c], inv = mv[2 * c + 1];
    size_t i = (size_t)c * 40000 + p;
    x[i] = fmaxf((x[i] - m) * inv * g[c] + b[c], 0.f);
}

// ---------------- 1x1 obj head ----------------
__global__ void obj_conv_k(const float* __restrict__ in, const float* __restrict__ w,
                           const float* __restrict__ bias, float* __restrict__ out) {
    int p = blockIdx.x * 256 + threadIdx.x;
    if (p >= 40000) return;
    float xin[48];
#pragma unroll
    for (int c = 0; c < 48; c++) xin[c] = in[(size_t)c * 40000 + p];
    for (int o = 0; o < NCLS; o++) {
        float acc = bias[o];
#pragma unroll
        for (int c = 0; c < 48; c++) acc += xin[c] * w[o * 48 + c];
        out[(size_t)o * 40000 + p] = acc;
    }
}

extern "C" void kernel_launch(void* const* d_in, const int* in_sizes, int n_in,
                              void* d_out, int out_size, void* d_ws, size_t ws_size,
                              hipStream_t stream) {
    const float* value   = (const float*)d_in[0];
    const float* bev_q   = (const float*)d_in[1];
    const float* bev_pos = (const float*)d_in[2];
    const int*   proj    = (const int*)d_in[3];
    const float* Wv      = (const float*)d_in[4];
    const float* bv      = (const float*)d_in[5];
    const float* Woff    = (const float*)d_in[6];
    const float* boff    = (const float*)d_in[7];
    const float* Wattn   = (const float*)d_in[8];
    const float* battn   = (const float*)d_in[9];
    const float* Wout    = (const float*)d_in[10];
    const float* bout    = (const float*)d_in[11];
    const float* Wf1     = (const float*)d_in[12];
    const float* bf1     = (const float*)d_in[13];
    const float* Wf2     = (const float*)d_in[14];
    const float* bf2     = (const float*)d_in[15];
    const float* ln_g    = (const float*)d_in[16];
    const float* ln_b    = (const float*)d_in[17];
    const float* cw1     = (const float*)d_in[18];
    const float* g1      = (const float*)d_in[19];
    const float* b1      = (const float*)d_in[20];
    const float* cw2     = (const float*)d_in[21];
    const float* g2      = (const float*)d_in[22];
    const float* b2      = (const float*)d_in[23];
    const float* cw3     = (const float*)d_in[24];
    const float* g3      = (const float*)d_in[25];
    const float* b3      = (const float*)d_in[26];
    const float* cw4     = (const float*)d_in[27];
    const float* g4      = (const float*)d_in[28];
    const float* b4      = (const float*)d_in[29];
    const float* objw    = (const float*)d_in[30];
    const float* objb    = (const float*)d_in[31];
    float* out = (float*)d_out;

    float* WSb = (float*)d_ws;
    float* q    = WSb + 0;            // 5,120,000
    float* qp   = WSb + 5120000;      // 5,120,000
    float* vbuf = WSb + 10240000;     // 5,570,560
    float* ao   = WSb + 15810560;     // 5,120,000
    float* tmp  = WSb + 20930560;     // 5,120,000
    float* offb = WSb + 26050560;     // 4,096,000
    float* attb = WSb + 30146560;     // 2,048,000
    int*   maxi = (int*)(WSb + 32194560);
    // conv-stage aliases (encoder buffers are dead by then)
    float* mem = qp;
    float* c1  = ao;
    float* c2  = tmp;
    float* c3  = offb;
    float* c4  = offb + 2048000;
    float* wT  = attb;
    float* bns = attb + 1048576;

    // ---- mask ----
    hipMemsetAsync(maxi, 0, sizeof(int), stream);
    reduce_max_int<<<157, 256, 0, stream>>>(proj, maxi);
    write_mask<<<157, 256, 0, stream>>>(proj, maxi, out + 840000);

    // ---- encoder ----
    hipMemcpyAsync(q, bev_q, (size_t)NQ * EDIM * sizeof(float),
                   hipMemcpyDeviceToDevice, stream);
    for (int l = 0; l < 2; l++) {
        gemm_bias_k<<<dim3(680, 2), 256, 0, stream>>>(
            value, Wv + (size_t)l * EDIM * EDIM, bv + (size_t)l * EDIM, vbuf, NVAL, EDIM, 0);
        add2_k<<<20000, 256, 0, stream>>>(q, bev_pos, qp, NQ * EDIM);
        for (int cidx = 0; cidx < 5; cidx++) {
            int qs = cidx * 8000;
            gemm_bias_k<<<dim3(125, 8), 256, 0, stream>>>(
                qp + (size_t)qs * EDIM, Woff + (size_t)l * EDIM * 512,
                boff + (size_t)l * 512, offb, 8000, 512, 0);
            gemm_bias_k<<<dim3(125, 4), 256, 0, stream>>>(
                qp + (size_t)qs * EDIM, Wattn + (size_t)l * EDIM * 256,
                battn + (size_t)l * 256, attb, 8000, 256, 0);
            deform_sample_k<<<4000, 256, 0, stream>>>(vbuf, offb, attb, ao, qs, 8000);
        }
        gemm_bias_k<<<dim3(625, 2), 256, 0, stream>>>(
            ao, Wout + (size_t)l * EDIM * EDIM, bout + (size_t)l * EDIM, tmp, NQ, EDIM, 0);
        add_ln_k<<<10000, 256, 0, stream>>>(q, tmp, ln_g + (size_t)(l * 2 + 0) * EDIM,
                                            ln_b + (size_t)(l * 2 + 0) * EDIM);
        gemm_bias_k<<<dim3(625, 2), 256, 0, stream>>>(
            q, Wf1 + (size_t)l * EDIM * EDIM, bf1 + (size_t)l * EDIM, ao, NQ, EDIM, 1);
        gemm_bias_k<<<dim3(625, 2), 256, 0, stream>>>(
            ao, Wf2 + (size_t)l * EDIM * EDIM, bf2 + (size_t)l * EDIM, tmp, NQ, EDIM, 0);
        add_ln_k<<<10000, 256, 0, stream>>>(q, tmp, ln_g + (size_t)(l * 2 + 1) * EDIM,
                                            ln_b + (size_t)(l * 2 + 1) * EDIM);
    }

    // ---- conv head ----
    transpose_qc_k<<<dim3(1250, 4), 256, 0, stream>>>(q, mem);

    repack_w_k<<<(128 * 128 * 49 + 255) / 256, 256, 0, stream>>>(cw1, wT, 128, 128, 7);
    conv_k<7, 3, 8><<<dim3(13, 13, 8), 256, 0, stream>>>(mem, wT, c1, 128, 128);
    bn_stats_k<<<128, 256, 0, stream>>>(c1, bns);
    bn_apply_k<<<dim3(157, 128), 256, 0, stream>>>(c1, bns, g1, b1);

    repack_w_k<<<(64 * 128 * 9 + 255) / 256, 256, 0, stream>>>(cw2, wT, 64, 128, 3);
    conv_k<3, 1, 16><<<dim3(13, 13, 4), 256, 0, stream>>>(c1, wT, c2, 128, 64);
    bn_stats_k<<<64, 256, 0, stream>>>(c2, bns);
    bn_apply_k<<<dim3(157, 64), 256, 0, stream>>>(c2, bns, g2, b2);

    repack_w_k<<<(48 * 64 * 9 + 255) / 256, 256, 0, stream>>>(cw3, wT, 48, 64, 3);
    conv_k<3, 1, 16><<<dim3(13, 13, 3), 256, 0, stream>>>(c2, wT, c3, 64, 48);
    bn_stats_k<<<48, 256, 0, stream>>>(c3, bns);
    bn_apply_k<<<dim3(157, 48), 256, 0, stream>>>(c3, bns, g3, b3);

    repack_w_k<<<(48 * 48 * 9 + 255) / 256, 256, 0, stream>>>(cw4, wT, 48, 48, 3);
    conv_k<3, 1, 16><<<dim3(13, 13, 3), 256, 0, stream>>>(c3, wT, c4, 48, 48);
    bn_stats_k<<<48, 256, 0, stream>>>(c4, bns);
    bn_apply_k<<<dim3(157, 48), 256, 0, stream>>>(c4, bns, g4, b4);

    obj_conv_k<<<157, 256, 0, stream>>>(c4, objw, objb, out);
}

// Round 2
// 3145.638 us; speedup vs baseline: 1.1647x; 1.1647x over previous
//
#include <hip/hip_runtime.h>
#include <cstdint>
#include <cstddef>

#define NQ 40000
#define EDIM 128
#define NVAL 43520
#define NCLS 21

typedef unsigned short u16;
typedef short bf16x8 __attribute__((ext_vector_type(8)));
typedef float f32x4 __attribute__((ext_vector_type(4)));

__device__ inline u16 f2b(float f) {
    unsigned u = __float_as_uint(f);
    unsigned r = u + 0x7FFF + ((u >> 16) & 1);
    return (u16)(r >> 16);
}
__device__ inline float b2f(u16 v) {
    unsigned u = ((unsigned)v) << 16;
    return __uint_as_float(u);
}

// ---------------- mask ----------------
__global__ void reduce_max_int(const int* __restrict__ idx, int* __restrict__ mx) {
    int i = blockIdx.x * 256 + threadIdx.x;
    int v = (i < NQ) ? idx[i] : 0;
    for (int o = 32; o > 0; o >>= 1) v = max(v, __shfl_xor(v, o, 64));
    if ((threadIdx.x & 63) == 0) atomicMax(mx, v);
}

__global__ void write_mask(const int* __restrict__ idx, const int* __restrict__ mx,
                           float* __restrict__ out) {
    int i = blockIdx.x * 256 + threadIdx.x;
    if (i >= NQ) return;
    out[i] = (idx[i] < *mx) ? 1.0f : 0.0f;
}

// ---------------- conversions / packing ----------------
// fp32 -> bf16, n multiple of 8
__global__ void cvt_b_k(const float* __restrict__ src, u16* __restrict__ dst, int n8) {
    int i = blockIdx.x * 256 + threadIdx.x;
    if (i >= n8) return;
    const float4 a = ((const float4*)src)[i * 2];
    const float4 b = ((const float4*)src)[i * 2 + 1];
    u16 o[8] = {f2b(a.x), f2b(a.y), f2b(a.z), f2b(a.w), f2b(b.x), f2b(b.y), f2b(b.z), f2b(b.w)};
    ((uint4*)dst)[i] = *(const uint4*)o;
}

// qpb = bf16(q + pos)
__global__ void add2b_k(const float* __restrict__ a, const float* __restrict__ b,
                        u16* __restrict__ c, int n8) {
    int i = blockIdx.x * 256 + threadIdx.x;
    if (i >= n8) return;
    const float4 a0 = ((const float4*)a)[i * 2], a1 = ((const float4*)a)[i * 2 + 1];
    const float4 b0 = ((const float4*)b)[i * 2], b1 = ((const float4*)b)[i * 2 + 1];
    u16 o[8] = {f2b(a0.x + b0.x), f2b(a0.y + b0.y), f2b(a0.z + b0.z), f2b(a0.w + b0.w),
                f2b(a1.x + b1.x), f2b(a1.y + b1.y), f2b(a1.z + b1.z), f2b(a1.w + b1.w)};
    ((uint4*)c)[i] = *(const uint4*)o;
}

// W [128][N] fp32 -> WT [N][128] bf16
__global__ void packWT_k(const float* __restrict__ W, u16* __restrict__ WT, int N) {
    int i = blockIdx.x * 256 + threadIdx.x;
    if (i >= 128 * N) return;
    int k = i / N, n = i - k * N;
    WT[n * 128 + k] = f2b(W[i]);
}

// cw [OC][IC][KS][KS] fp32 -> wT [KS*KS][OCp][ICp] bf16 (zero-padded)
__global__ void pack_cw_k(const float* __restrict__ w, u16* __restrict__ wT,
                          int OC, int IC, int KS, int OCp, int ICp) {
    int i = blockIdx.x * 256 + threadIdx.x;
    int tot = KS * KS * OCp * ICp;
    if (i >= tot) return;
    int ic = i % ICp; int r = i / ICp;
    int oc = r % OCp; int tap = r / OCp;
    int ky = tap / KS, kx = tap % KS;
    float v = 0.f;
    if (oc < OC && ic < IC)
        v = w[(((size_t)oc * IC + ic) * KS + ky) * KS + kx];
    wT[i] = f2b(v);
}

// ---------------- MFMA GEMM: C[M][N] = A[M][128] @ BT^T + bias ----------------
// A bf16 [M][128], BT bf16 [N][128]. M,N multiples of 64.
__global__ __launch_bounds__(256) void gemm_mfma_k(
        const u16* __restrict__ A, const u16* __restrict__ BT,
        const float* __restrict__ bias, float* __restrict__ Cf,
        u16* __restrict__ Cb, int N, int relu) {
    __shared__ u16 As[64 * 136];
    __shared__ u16 Bs[64 * 136];
    const int m0 = blockIdx.x * 64, n0 = blockIdx.y * 64;
    const int t = threadIdx.x;
#pragma unroll
    for (int ci = t; ci < 1024; ci += 256) {
        int r = ci >> 4, c = ci & 15;
        *(uint4*)&As[r * 136 + c * 8] = *(const uint4*)&A[(size_t)(m0 + r) * 128 + c * 8];
        *(uint4*)&Bs[r * 136 + c * 8] = *(const uint4*)&BT[(size_t)(n0 + r) * 128 + c * 8];
    }
    __syncthreads();
    const int wave = t >> 6, lane = t & 63;
    const int wm = (wave & 1) * 32, wn = (wave >> 1) * 32;
    const int lr = lane & 15, lk = (lane >> 4) * 8;
    f32x4 acc[2][2] = {};
#pragma unroll
    for (int ks = 0; ks < 4; ks++) {
        bf16x8 a0 = *(const bf16x8*)&As[(wm + lr) * 136 + ks * 32 + lk];
        bf16x8 a1 = *(const bf16x8*)&As[(wm + 16 + lr) * 136 + ks * 32 + lk];
        bf16x8 b0 = *(const bf16x8*)&Bs[(wn + lr) * 136 + ks * 32 + lk];
        bf16x8 b1 = *(const bf16x8*)&Bs[(wn + 16 + lr) * 136 + ks * 32 + lk];
        acc[0][0] = __builtin_amdgcn_mfma_f32_16x16x32_bf16(a0, b0, acc[0][0], 0, 0, 0);
        acc[0][1] = __builtin_amdgcn_mfma_f32_16x16x32_bf16(a0, b1, acc[0][1], 0, 0, 0);
        acc[1][0] = __builtin_amdgcn_mfma_f32_16x16x32_bf16(a1, b0, acc[1][0], 0, 0, 0);
        acc[1][1] = __builtin_amdgcn_mfma_f32_16x16x32_bf16(a1, b1, acc[1][1], 0, 0, 0);
    }
    float bj0 = bias[n0 + wn + lr];
    float bj1 = bias[n0 + wn + 16 + lr];
#pragma unroll
    for (int i = 0; i < 2; i++) {
#pragma unroll
        for (int j = 0; j < 2; j++) {
            float bb = j ? bj1 : bj0;
#pragma unroll
            for (int r = 0; r < 4; r++) {
                int ml = wm + i * 16 + (lane >> 4) * 4 + r;
                int nl = wn + j * 16 + lr;
                float v = acc[i][j][r] + bb;
                if (relu) v = fmaxf(v, 0.f);
                size_t o = (size_t)(m0 + ml) * N + n0 + nl;
                if (Cf) Cf[o] = v;
                if (Cb) Cb[o] = f2b(v);
            }
        }
    }
}

// ---------------- MFMA implicit-GEMM conv ----------------
// in bf16 [40000][ICp], wT bf16 [KS*KS][OCp][ICp], out fp32 [40000][OCp]
template <int KS, int PAD>
__global__ __launch_bounds__(256) void conv_mfma_k(
        const u16* __restrict__ in, const u16* __restrict__ wT,
        float* __restrict__ out, int ICp, int OCp, int cprSh, int ksteps) {
    __shared__ u16 As[64 * 136];
    __shared__ u16 Bs[64 * 136];
    const int m0 = blockIdx.x * 64, n0 = blockIdx.y * 64;
    const int t = threadIdx.x;
    const int wave = t >> 6, lane = t & 63;
    const int wm = (wave & 1) * 32, wn = (wave >> 1) * 32;
    const int lr = lane & 15, lk = (lane >> 4) * 8;
    const int cprM = (1 << cprSh) - 1;
    const int totA = 64 << cprSh;
    f32x4 acc[2][2] = {};
    for (int tap = 0; tap < KS * KS; tap++) {
        const int ky = tap / KS, kx = tap % KS;
        const int doff = (ky - PAD) * 200 + (kx - PAD);
        const u16* wt = wT + (size_t)tap * OCp * ICp + (size_t)n0 * ICp;
        for (int ci = t; ci < totA; ci += 256) {
            int r = ci >> cprSh, c = ci & cprM;
            int p = m0 + r;
            int y = p / 200, x = p - y * 200;
            int sy = y + ky - PAD, sx = x + kx - PAD;
            uint4 v = {0u, 0u, 0u, 0u};
            if ((unsigned)sy < 200u && (unsigned)sx < 200u)
                v = *(const uint4*)&in[(size_t)(p + doff) * ICp + c * 8];
            *(uint4*)&As[r * 136 + c * 8] = v;
        }
        for (int ci = t; ci < totA; ci += 256) {
            int r = ci >> cprSh, c = ci & cprM;
            *(uint4*)&Bs[r * 136 + c * 8] = *(const uint4*)&wt[(size_t)r * ICp + c * 8];
        }
        __syncthreads();
        for (int ks = 0; ks < ksteps; ks++) {
            bf16x8 a0 = *(const bf16x8*)&As[(wm + lr) * 136 + ks * 32 + lk];
            bf16x8 a1 = *(const bf16x8*)&As[(wm + 16 + lr) * 136 + ks * 32 + lk];
            bf16x8 b0 = *(const bf16x8*)&Bs[(wn + lr) * 136 + ks * 32 + lk];
            bf16x8 b1 = *(const bf16x8*)&Bs[(wn + 16 + lr) * 136 + ks * 32 + lk];
            acc[0][0] = __builtin_amdgcn_mfma_f32_16x16x32_bf16(a0, b0, acc[0][0], 0, 0, 0);
            acc[0][1] = __builtin_amdgcn_mfma_f32_16x16x32_bf16(a0, b1, acc[0][1], 0, 0, 0);
            acc[1][0] = __builtin_amdgcn_mfma_f32_16x16x32_bf16(a1, b0, acc[1][0], 0, 0, 0);
            acc[1][1] = __builtin_amdgcn_mfma_f32_16x16x32_bf16(a1, b1, acc[1][1], 0, 0, 0);
        }
        __syncthreads();
    }
#pragma unroll
    for (int i = 0; i < 2; i++) {
#pragma unroll
        for (int j = 0; j < 2; j++) {
#pragma unroll
            for (int r = 0; r < 4; r++) {
                int ml = wm + i * 16 + (lane >> 4) * 4 + r;
                int nl = wn + j * 16 + lr;
                out[(size_t)(m0 + ml) * OCp + n0 + nl] = acc[i][j][r];
            }
        }
    }
}

// ---------------- deformable sampling (softmax fused), bf16 value ----------------
__global__ __launch_bounds__(256) void deform_sample_k(
        const u16* __restrict__ v, const float* __restrict__ off,
        const float* __restrict__ logits, u16* __restrict__ outb,
        int q0, int nq) {
    const int t = threadIdx.x;
    const int sub = t >> 7;
    const int h = (t >> 4) & 7;
    const int d = t & 15;
    const int qi = blockIdx.x * 2 + sub;
    if (qi >= nq) return;
    const int gq = q0 + qi;
    const float rx = ((gq % 200) + 0.5f) / 200.f;
    const float ry = ((gq / 200) + 0.5f) / 200.f;
    const float* offp = off + (size_t)qi * 512 + h * 64;
    const float* logp = logits + (size_t)qi * 256 + h * 32;
    float lg[32];
    float mx = -1e30f;
#pragma unroll
    for (int i = 0; i < 32; i++) { lg[i] = logp[i]; mx = fmaxf(mx, lg[i]); }
    float ssum = 0.f;
#pragma unroll
    for (int i = 0; i < 32; i++) { lg[i] = __expf(lg[i] - mx); ssum += lg[i]; }
    const float inv = 1.f / ssum;

    const int HS[4] = {128, 64, 32, 16};
    const int WS[4] = {256, 128, 64, 32};
    const int ST[4] = {0, 32768, 40960, 43008};
    float acc = 0.f;
#pragma unroll
    for (int l = 0; l < 4; l++) {
        const int H = HS[l], W = WS[l], start = ST[l];
        const float fW = (float)W, fH = (float)H;
#pragma unroll
        for (int p = 0; p < 8; p++) {
            float ox = offp[(l * 8 + p) * 2 + 0];
            float oy = offp[(l * 8 + p) * 2 + 1];
            float x = rx * fW + ox - 0.5f;
            float y = ry * fH + oy - 0.5f;
            float x0 = floorf(x), y0 = floorf(y);
            float aw = lg[l * 8 + p] * inv;
#pragma unroll
            for (int cy = 0; cy < 2; cy++) {
#pragma unroll
                for (int cx = 0; cx < 2; cx++) {
                    float xc = x0 + cx, yc = y0 + cy;
                    float wgt = (1.f - fabsf(x - xc)) * (1.f - fabsf(y - yc));
                    bool valid = (xc >= 0.f) && (xc < fW) && (yc >= 0.f) && (yc < fH);
                    int xi = min(max((int)xc, 0), W - 1);
                    int yi = min(max((int)yc, 0), H - 1);
                    float val = b2f(v[(size_t)(start + yi * W + xi) * 128 + h * 16 + d]);
                    acc += valid ? (aw * wgt * val) : 0.f;
                }
            }
        }
    }
    outb[(size_t)gq * 128 + h * 16 + d] = f2b(acc);
}

// ---------------- fused residual + layernorm (q fp32 in/out, qb bf16 out) ----------------
__global__ __launch_bounds__(256) void add_ln_k(
        float* __restrict__ q, const float* __restrict__ a,
        const float* __restrict__ g, const float* __restrict__ b,
        u16* __restrict__ qb) {
    const int row = blockIdx.x * 4 + (threadIdx.x >> 6);
    const int lane = threadIdx.x & 63;
    float s0 = q[(size_t)row * 128 + lane] + a[(size_t)row * 128 + lane];
    float s1 = q[(size_t)row * 128 + 64 + lane] + a[(size_t)row * 128 + 64 + lane];
    float sum = s0 + s1;
    for (int o = 32; o > 0; o >>= 1) sum += __shfl_xor(sum, o, 64);
    float mean = sum * (1.f / 128.f);
    float d0 = s0 - mean, d1 = s1 - mean;
    float vs = d0 * d0 + d1 * d1;
    for (int o = 32; o > 0; o >>= 1) vs += __shfl_xor(vs, o, 64);
    float inv = rsqrtf(vs * (1.f / 128.f) + 1e-5f);
    float o0 = d0 * inv * g[lane] + b[lane];
    float o1 = d1 * inv * g[64 + lane] + b[64 + lane];
    q[(size_t)row * 128 + lane] = o0;
    q[(size_t)row * 128 + 64 + lane] = o1;
    qb[(size_t)row * 128 + lane] = f2b(o0);
    qb[(size_t)row * 128 + 64 + lane] = f2b(o1);
}

// ---------------- BN stats (coalesced, atomic accumulation) ----------------
__global__ __launch_bounds__(256) void bn_stats2_k(const float* __restrict__ x,
                                                   float* __restrict__ acc,
                                                   int cSh, int ppb) {
    const int t = threadIdx.x;
    const int Cp = 1 << cSh;
    const int c = t & (Cp - 1);
    const int sub = t >> cSh;
    const int nsub = 256 >> cSh;
    float s = 0.f, s2 = 0.f;
    const int pbase = blockIdx.x * ppb;
    for (int i = sub; i < ppb; i += nsub) {
        float v = x[(size_t)(pbase + i) * Cp + c];
        s += v; s2 += v * v;
    }
    __shared__ float ls[256], ls2[256];
    ls[t] = s; ls2[t] = s2;
    __syncthreads();
    if (t < Cp) {
        for (int k = 1; k < nsub; k++) { s += ls[t + k * Cp]; s2 += ls2[t + k * Cp]; }
        atomicAdd(&acc[2 * t], s);
        atomicAdd(&acc[2 * t + 1], s2);
    }
}

__global__ void bn_fin_k(const float* __restrict__ acc, float* __restrict__ mv, int C) {
    int t = threadIdx.x;
    if (t >= C) return;
    float m = acc[2 * t] * (1.f / 40000.f);
    float var = acc[2 * t + 1] * (1.f / 40000.f) - m * m;
    mv[2 * t] = m;
    mv[2 * t + 1] = rsqrtf(var + 1e-5f);
}

__global__ void bn_apply2_k(const float* __restrict__ x, const float* __restrict__ mv,
                            const float* __restrict__ g, const float* __restrict__ b,
                            u16* __restrict__ outb, int cSh, int Creal) {
    int i = blockIdx.x * 256 + threadIdx.x;
    int Cp = 1 << cSh;
    if (i >= 40000 * Cp) return;
    int c = i & (Cp - 1);
    float v = 0.f;
    if (c < Creal) v = fmaxf((x[i] - mv[2 * c]) * mv[2 * c + 1] * g[c] + b[c], 0.f);
    outb[i] = f2b(v);
}

// ---------------- 1x1 obj head (bf16 in [p][64], 48 real ch) ----------------
__global__ void obj_conv_k(const u16* __restrict__ in, const float* __restrict__ w,
                           const float* __restrict__ bias, float* __restrict__ out) {
    int p = blockIdx.x * 256 + threadIdx.x;
    if (p >= 40000) return;
    float xin[48];
#pragma unroll
    for (int c = 0; c < 48; c++) xin[c] = b2f(in[(size_t)p * 64 + c]);
    for (int o = 0; o < NCLS; o++) {
        float acc = bias[o];
#pragma unroll
        for (int c = 0; c < 48; c++) acc += xin[c] * w[o * 48 + c];
        out[(size_t)o * 40000 + p] = acc;
    }
}

extern "C" void kernel_launch(void* const* d_in, const int* in_sizes, int n_in,
                              void* d_out, int out_size, void* d_ws, size_t ws_size,
                              hipStream_t stream) {
    const float* value   = (const float*)d_in[0];
    const float* bev_q   = (const float*)d_in[1];
    const float* bev_pos = (const float*)d_in[2];
    const int*   proj    = (const int*)d_in[3];
    const float* Wv      = (const float*)d_in[4];
    const float* bv      = (const float*)d_in[5];
    const float* Woff    = (const float*)d_in[6];
    const float* boff    = (const float*)d_in[7];
    const float* Wattn   = (const float*)d_in[8];
    const float* battn   = (const float*)d_in[9];
    const float* Wout    = (const float*)d_in[10];
    const float* bout    = (const float*)d_in[11];
    const float* Wf1     = (const float*)d_in[12];
    const float* bf1     = (const float*)d_in[13];
    const float* Wf2     = (const float*)d_in[14];
    const float* bf2     = (const float*)d_in[15];
    const float* ln_g    = (const float*)d_in[16];
    const float* ln_b    = (const float*)d_in[17];
    const float* cw1     = (const float*)d_in[18];
    const float* g1      = (const float*)d_in[19];
    const float* b1      = (const float*)d_in[20];
    const float* cw2     = (const float*)d_in[21];
    const float* g2      = (const float*)d_in[22];
    const float* b2      = (const float*)d_in[23];
    const float* cw3     = (const float*)d_in[24];
    const float* g3      = (const float*)d_in[25];
    const float* b3      = (const float*)d_in[26];
    const float* cw4     = (const float*)d_in[27];
    const float* g4      = (const float*)d_in[28];
    const float* b4      = (const float*)d_in[29];
    const float* objw    = (const float*)d_in[30];
    const float* objb    = (const float*)d_in[31];
    float* out = (float*)d_out;

    float* WSb = (float*)d_ws;
    // float-unit offsets
    float* q     = WSb + 0;                       // 5,120,000 f
    u16*   qb    = (u16*)(WSb + 5120000);         // 2,560,000 f
    u16*   qpb   = (u16*)(WSb + 7680000);         // 2,560,000 f
    u16*   valb  = (u16*)(WSb + 10240000);        // 2,785,280 f
    u16*   vbufb = (u16*)(WSb + 13025280);        // 2,785,280 f
    float* offb  = WSb + 15810560;                // 4,096,000 f
    float* attb  = WSb + 19906560;                // 2,048,000 f
    float* tmp   = WSb + 15810560;                // aliases offb/attb (disjoint in time)
    u16*   aob   = (u16*)(WSb + 21954560);        // 2,560,000 f
    u16*   hb    = (u16*)(WSb + 24514560);        // 2,560,000 f
    u16*   wenc  = (u16*)(WSb + 27074560);        // 163,840 f (2 layers x 81,920)
    u16*   wcv   = (u16*)(WSb + 27238240);        // 475,136 f
    float* bnacc = WSb + 27713376;                // 512 f (acc) + 256 f (mv)
    float* bnmv  = WSb + 27713888;
    int*   maxi  = (int*)(WSb + 27714400);

    // conv-stage aliases (encoder-only buffers dead by then)
    float* c1f = tmp;                  // 5.12M f
    u16*   c1b = (u16*)(WSb + 0);      // over q
    float* c2f = WSb + 10240000;       // over valb
    u16*   c2b = (u16*)(WSb + 13025280); // over vbufb
    float* c3f = WSb + 21954560;       // over aob
    u16*   c3b = (u16*)(WSb + 24514560); // over hb (first half)
    float* c4f = WSb + 7680000;        // over qpb
    u16*   c4b = (u16*)(WSb + 25794560); // over hb (second half)

    // per-layer packed weight offsets (in u16 units)
    const int L = 81920 * 2; // u16 per layer
    u16* WvT[2]; u16* WoffT[2]; u16* WattnT[2]; u16* WoutT[2]; u16* Wf1T[2]; u16* Wf2T[2];
    for (int l = 0; l < 2; l++) {
        u16* base = wenc + (size_t)l * L;
        WvT[l]    = base;             // 16384
        WoffT[l]  = base + 16384;     // 65536
        WattnT[l] = base + 81920;     // 32768
        WoutT[l]  = base + 114688;    // 16384
        Wf1T[l]   = base + 131072;    // 16384
        Wf2T[l]   = base + 147456;    // 16384
    }
    u16* w1T = wcv;                   // 49*128*128 = 802816
    u16* w2T = wcv + 802816;          // 9*64*128   = 73728
    u16* w3T = wcv + 876544;          // 9*64*64    = 36864
    u16* w4T = wcv + 913408;          // 9*64*64    = 36864

    // ---- mask ----
    hipMemsetAsync(maxi, 0, sizeof(int), stream);
    reduce_max_int<<<157, 256, 0, stream>>>(proj, maxi);
    write_mask<<<157, 256, 0, stream>>>(proj, maxi, out + 840000);

    // ---- weight packing (all small) ----
    for (int l = 0; l < 2; l++) {
        packWT_k<<<64, 256, 0, stream>>>(Wv + (size_t)l * 128 * 128, WvT[l], 128);
        packWT_k<<<256, 256, 0, stream>>>(Woff + (size_t)l * 128 * 512, WoffT[l], 512);
        packWT_k<<<128, 256, 0, stream>>>(Wattn + (size_t)l * 128 * 256, WattnT[l], 256);
        packWT_k<<<64, 256, 0, stream>>>(Wout + (size_t)l * 128 * 128, WoutT[l], 128);
        packWT_k<<<64, 256, 0, stream>>>(Wf1 + (size_t)l * 128 * 128, Wf1T[l], 128);
        packWT_k<<<64, 256, 0, stream>>>(Wf2 + (size_t)l * 128 * 128, Wf2T[l], 128);
    }
    pack_cw_k<<<3136, 256, 0, stream>>>(cw1, w1T, 128, 128, 7, 128, 128);
    pack_cw_k<<<288, 256, 0, stream>>>(cw2, w2T, 64, 128, 3, 64, 128);
    pack_cw_k<<<144, 256, 0, stream>>>(cw3, w3T, 48, 64, 3, 64, 64);
    pack_cw_k<<<144, 256, 0, stream>>>(cw4, w4T, 48, 48, 3, 64, 64);

    // ---- value -> bf16 once ----
    cvt_b_k<<<2720, 256, 0, stream>>>(value, valb, NVAL * 128 / 8);

    // ---- encoder ----
    hipMemcpyAsync(q, bev_q, (size_t)NQ * EDIM * sizeof(float),
                   hipMemcpyDeviceToDevice, stream);
    for (int l = 0; l < 2; l++) {
        gemm_mfma_k<<<dim3(680, 2), 256, 0, stream>>>(
            valb, WvT[l], bv + (size_t)l * 128, nullptr, vbufb, 128, 0);
        add2b_k<<<2500, 256, 0, stream>>>(q, bev_pos, qpb, NQ * 128 / 8);
        for (int cidx = 0; cidx < 5; cidx++) {
            int qs = cidx * 8000;
            gemm_mfma_k<<<dim3(125, 8), 256, 0, stream>>>(
                qpb + (size_t)qs * 128, WoffT[l], boff + (size_t)l * 512,
                offb, nullptr, 512, 0);
            gemm_mfma_k<<<dim3(125, 4), 256, 0, stream>>>(
                qpb + (size_t)qs * 128, WattnT[l], battn + (size_t)l * 256,
                attb, nullptr, 256, 0);
            deform_sample_k<<<4000, 256, 0, stream>>>(vbufb, offb, attb, aob, qs, 8000);
        }
        gemm_mfma_k<<<dim3(625, 2), 256, 0, stream>>>(
            aob, WoutT[l], bout + (size_t)l * 128, tmp, nullptr, 128, 0);
        add_ln_k<<<10000, 256, 0, stream>>>(q, tmp, ln_g + (size_t)(l * 2 + 0) * 128,
                                            ln_b + (size_t)(l * 2 + 0) * 128, qb);
        gemm_mfma_k<<<dim3(625, 2), 256, 0, stream>>>(
            qb, Wf1T[l], bf1 + (size_t)l * 128, nullptr, hb, 128, 1);
        gemm_mfma_k<<<dim3(625, 2), 256, 0, stream>>>(
            hb, Wf2T[l], bf2 + (size_t)l * 128, tmp, nullptr, 128, 0);
        add_ln_k<<<10000, 256, 0, stream>>>(q, tmp, ln_g + (size_t)(l * 2 + 1) * 128,
                                            ln_b + (size_t)(l * 2 + 1) * 128, qb);
    }

    // ---- conv head (implicit-GEMM MFMA; activations bf16 [pixel][C]) ----
    // conv1: IC=128 OC=128 7x7
    conv_mfma_k<7, 3><<<dim3(625, 2), 256, 0, stream>>>(qb, w1T, c1f, 128, 128, 4, 4);
    hipMemsetAsync(bnacc, 0, 512 * sizeof(float), stream);
    bn_stats2_k<<<125, 256, 0, stream>>>(c1f, bnacc, 7, 320);
    bn_fin_k<<<1, 128, 0, stream>>>(bnacc, bnmv, 128);
    bn_apply2_k<<<20000, 256, 0, stream>>>(c1f, bnmv, g1, b1, c1b, 7, 128);

    // conv2: IC=128 OC=64 3x3
    conv_mfma_k<3, 1><<<dim3(625, 1), 256, 0, stream>>>(c1b, w2T, c2f, 128, 64, 4, 4);
    hipMemsetAsync(bnacc, 0, 512 * sizeof(float), stream);
    bn_stats2_k<<<125, 256, 0, stream>>>(c2f, bnacc, 6, 320);
    bn_fin_k<<<1, 64, 0, stream>>>(bnacc, bnmv, 64);
    bn_apply2_k<<<10000, 256, 0, stream>>>(c2f, bnmv, g2, b2, c2b, 6, 64);

    // conv3: IC=64 OC=48(pad 64) 3x3
    conv_mfma_k<3, 1><<<dim3(625, 1), 256, 0, stream>>>(c2b, w3T, c3f, 64, 64, 3, 2);
    hipMemsetAsync(bnacc, 0, 512 * sizeof(float), stream);
    bn_stats2_k<<<125, 256, 0, stream>>>(c3f, bnacc, 6, 320);
    bn_fin_k<<<1, 48, 0, stream>>>(bnacc, bnmv, 48);
    bn_apply2_k<<<10000, 256, 0, stream>>>(c3f, bnmv, g3, b3, c3b, 6, 48);

    // conv4: IC=48(pad 64) OC=48(pad 64) 3x3
    conv_mfma_k<3, 1><<<dim3(625, 1), 256, 0, stream>>>(c3b, w4T, c4f, 64, 64, 3, 2);
    hipMemsetAsync(bnacc, 0, 512 * sizeof(float), stream);
    bn_stats2_k<<<125, 256, 0, stream>>>(c4f, bnacc, 6, 320);
    bn_fin_k<<<1, 48, 0, stream>>>(bnacc, bnmv, 48);
    bn_apply2_k<<<10000, 256, 0, stream>>>(c4f, bnmv, g4, b4, c4b, 6, 48);

    obj_conv_k<<<157, 256, 0, stream>>>(c4b, objw, objb, out);
}

// Round 3
// 1374.717 us; speedup vs baseline: 2.6650x; 2.2882x over previous
//
#include <hip/hip_runtime.h>
#include <cstdint>
#include <cstddef>

#define NQ 40000
#define EDIM 128
#define NVAL 43520
#define NCLS 21

typedef unsigned short u16;
typedef unsigned int uint;
typedef short bf16x8 __attribute__((ext_vector_type(8)));
typedef float f32x4 __attribute__((ext_vector_type(4)));

__device__ inline u16 f2b(float f) {
    unsigned u = __float_as_uint(f);
    unsigned r = u + 0x7FFF + ((u >> 16) & 1);
    return (u16)(r >> 16);
}
__device__ inline float b2f(u16 v) {
    unsigned u = ((unsigned)v) << 16;
    return __uint_as_float(u);
}
__device__ inline float blo(uint u) { return __uint_as_float(u << 16); }
__device__ inline float bhi(uint u) { return __uint_as_float(u & 0xFFFF0000u); }

// ---------------- mask ----------------
__global__ void reduce_max_int(const int* __restrict__ idx, int* __restrict__ mx) {
    int i = blockIdx.x * 256 + threadIdx.x;
    int v = (i < NQ) ? idx[i] : 0;
    for (int o = 32; o > 0; o >>= 1) v = max(v, __shfl_xor(v, o, 64));
    if ((threadIdx.x & 63) == 0) atomicMax(mx, v);
}

__global__ void write_mask(const int* __restrict__ idx, const int* __restrict__ mx,
                           float* __restrict__ out) {
    int i = blockIdx.x * 256 + threadIdx.x;
    if (i >= NQ) return;
    out[i] = (idx[i] < *mx) ? 1.0f : 0.0f;
}

// ---------------- conversions / packing ----------------
__global__ void cvt_b_k(const float* __restrict__ src, u16* __restrict__ dst, int n8) {
    int i = blockIdx.x * 256 + threadIdx.x;
    if (i >= n8) return;
    const float4 a = ((const float4*)src)[i * 2];
    const float4 b = ((const float4*)src)[i * 2 + 1];
    u16 o[8] = {f2b(a.x), f2b(a.y), f2b(a.z), f2b(a.w), f2b(b.x), f2b(b.y), f2b(b.z), f2b(b.w)};
    ((uint4*)dst)[i] = *(const uint4*)o;
}

__global__ void add2b_k(const float* __restrict__ a, const float* __restrict__ b,
                        u16* __restrict__ c, int n8) {
    int i = blockIdx.x * 256 + threadIdx.x;
    if (i >= n8) return;
    const float4 a0 = ((const float4*)a)[i * 2], a1 = ((const float4*)a)[i * 2 + 1];
    const float4 b0 = ((const float4*)b)[i * 2], b1 = ((const float4*)b)[i * 2 + 1];
    u16 o[8] = {f2b(a0.x + b0.x), f2b(a0.y + b0.y), f2b(a0.z + b0.z), f2b(a0.w + b0.w),
                f2b(a1.x + b1.x), f2b(a1.y + b1.y), f2b(a1.z + b1.z), f2b(a1.w + b1.w)};
    ((uint4*)c)[i] = *(const uint4*)o;
}

// fused encoder weight pack: all 6 matrices x 2 layers -> [n][128] bf16
__global__ void pack_enc_k(const float* __restrict__ Wv, const float* __restrict__ Woff,
                           const float* __restrict__ Wattn, const float* __restrict__ Wout,
                           const float* __restrict__ Wf1, const float* __restrict__ Wf2,
                           u16* __restrict__ dst) {
    int i = blockIdx.x * 256 + threadIdx.x;
    if (i >= 327680) return;
    int l = i / 163840, r = i % 163840;
    int k = r / 1280, col = r % 1280;
    const float* src; int N; int n; u16* d;
    u16* base = dst + (size_t)l * 163840;
    if (col < 128)       { src = Wv    + (size_t)l * 16384; N = 128; n = col;        d = base;          }
    else if (col < 640)  { src = Woff  + (size_t)l * 65536; N = 512; n = col - 128;  d = base + 16384;  }
    else if (col < 896)  { src = Wattn + (size_t)l * 32768; N = 256; n = col - 640;  d = base + 81920;  }
    else if (col < 1024) { src = Wout  + (size_t)l * 16384; N = 128; n = col - 896;  d = base + 114688; }
    else if (col < 1152) { src = Wf1   + (size_t)l * 16384; N = 128; n = col - 1024; d = base + 131072; }
    else                 { src = Wf2   + (size_t)l * 16384; N = 128; n = col - 1152; d = base + 147456; }
    d[(size_t)n * 128 + k] = f2b(src[(size_t)k * N + n]);
}

// cw [OC][IC][KS][KS] fp32 -> wT [KS*KS][OCp][ICp] bf16 (zero-padded)
__global__ void pack_cw_k(const float* __restrict__ w, u16* __restrict__ wT,
                          int OC, int IC, int KS, int OCp, int ICp) {
    int i = blockIdx.x * 256 + threadIdx.x;
    int tot = KS * KS * OCp * ICp;
    if (i >= tot) return;
    int ic = i % ICp; int r = i / ICp;
    int oc = r % OCp; int tap = r / OCp;
    int ky = tap / KS, kx = tap % KS;
    float v = 0.f;
    if (oc < OC && ic < IC)
        v = w[(((size_t)oc * IC + ic) * KS + ky) * KS + kx];
    wT[i] = f2b(v);
}

// ---------------- MFMA GEMM: C[M][N] = A[M][128] @ BT^T + bias ----------------
__global__ __launch_bounds__(256) void gemm_mfma_k(
        const u16* __restrict__ A, const u16* __restrict__ BT,
        const float* __restrict__ bias, float* __restrict__ Cf,
        u16* __restrict__ Cb, int N, int relu) {
    __shared__ u16 As[64 * 136];
    __shared__ u16 Bs[64 * 136];
    const int m0 = blockIdx.x * 64, n0 = blockIdx.y * 64;
    const int t = threadIdx.x;
#pragma unroll
    for (int ci = t; ci < 1024; ci += 256) {
        int r = ci >> 4, c = ci & 15;
        *(uint4*)&As[r * 136 + c * 8] = *(const uint4*)&A[(size_t)(m0 + r) * 128 + c * 8];
        *(uint4*)&Bs[r * 136 + c * 8] = *(const uint4*)&BT[(size_t)(n0 + r) * 128 + c * 8];
    }
    __syncthreads();
    const int wave = t >> 6, lane = t & 63;
    const int wm = (wave & 1) * 32, wn = (wave >> 1) * 32;
    const int lr = lane & 15, lk = (lane >> 4) * 8;
    f32x4 acc[2][2] = {};
#pragma unroll
    for (int ks = 0; ks < 4; ks++) {
        bf16x8 a0 = *(const bf16x8*)&As[(wm + lr) * 136 + ks * 32 + lk];
        bf16x8 a1 = *(const bf16x8*)&As[(wm + 16 + lr) * 136 + ks * 32 + lk];
        bf16x8 b0 = *(const bf16x8*)&Bs[(wn + lr) * 136 + ks * 32 + lk];
        bf16x8 b1 = *(const bf16x8*)&Bs[(wn + 16 + lr) * 136 + ks * 32 + lk];
        acc[0][0] = __builtin_amdgcn_mfma_f32_16x16x32_bf16(a0, b0, acc[0][0], 0, 0, 0);
        acc[0][1] = __builtin_amdgcn_mfma_f32_16x16x32_bf16(a0, b1, acc[0][1], 0, 0, 0);
        acc[1][0] = __builtin_amdgcn_mfma_f32_16x16x32_bf16(a1, b0, acc[1][0], 0, 0, 0);
        acc[1][1] = __builtin_amdgcn_mfma_f32_16x16x32_bf16(a1, b1, acc[1][1], 0, 0, 0);
    }
    float bj0 = bias[n0 + wn + lr];
    float bj1 = bias[n0 + wn + 16 + lr];
#pragma unroll
    for (int i = 0; i < 2; i++) {
#pragma unroll
        for (int j = 0; j < 2; j++) {
            float bb = j ? bj1 : bj0;
#pragma unroll
            for (int r = 0; r < 4; r++) {
                int ml = wm + i * 16 + (lane >> 4) * 4 + r;
                int nl = wn + j * 16 + lr;
                float v = acc[i][j][r] + bb;
                if (relu) v = fmaxf(v, 0.f);
                size_t o = (size_t)(m0 + ml) * N + n0 + nl;
                if (Cf) Cf[o] = v;
                if (Cb) Cb[o] = f2b(v);
            }
        }
    }
}

// ---------------- conv via padded image, per-ky A staging, register B ----------------
// pimg: padded [206][208][ICP] bf16 (3px border frame, zeroed)
// wT: [KS*KS][OCtot][ICP] bf16 ; out: [40000][OCtot] fp32
template <int KS, int ICP>
__global__ __launch_bounds__(256) void conv2_mfma_k(
        const u16* __restrict__ pimg, const u16* __restrict__ wT,
        float* __restrict__ out, int OCtot) {
    constexpr int PAD = KS / 2;
    constexpr int WIN = 64 + KS - 1;
    constexpr int LDSTR = ICP + 8;
    constexpr int KSTEPS = ICP / 32;
    constexpr int CHUNKS = WIN * (ICP / 8);
    __shared__ u16 As[WIN * LDSTR];
    const int bx = blockIdx.x;
    const int y = bx >> 2;
    const int xc = bx & 3;
    const int x0 = (xc == 3) ? 136 : xc * 64;
    const int n0 = blockIdx.y * 64;
    const int t = threadIdx.x;
    const int wave = t >> 6, lane = t & 63;
    const int wm = (wave & 1) * 32, wn = (wave >> 1) * 32;
    const int lr = lane & 15, lkq = lane >> 4;
    const int lk = lkq * 8;
    f32x4 acc[2][2] = {};
    for (int ky = 0; ky < KS; ky++) {
        __syncthreads();
        const int prow = y + ky + 3 - PAD;
        const int pcol = x0 + 3 - PAD;
        const u16* src = pimg + ((size_t)prow * 208 + pcol) * ICP;
        for (int ci = t; ci < CHUNKS; ci += 256) {
            int r = ci / (ICP / 8), c = ci - r * (ICP / 8);
            *(uint4*)&As[r * LDSTR + c * 8] = *(const uint4*)&src[(size_t)r * ICP + c * 8];
        }
        __syncthreads();
        for (int kx = 0; kx < KS; kx++) {
            const int tap = ky * KS + kx;
            const u16* wb = wT + ((size_t)tap * OCtot + n0) * ICP;
            bf16x8 b0r[KSTEPS], b1r[KSTEPS];
#pragma unroll
            for (int ks = 0; ks < KSTEPS; ks++) {
                b0r[ks] = *(const bf16x8*)&wb[(size_t)(wn + lr) * ICP + ks * 32 + lk];
                b1r[ks] = *(const bf16x8*)&wb[(size_t)(wn + 16 + lr) * ICP + ks * 32 + lk];
            }
#pragma unroll
            for (int ks = 0; ks < KSTEPS; ks++) {
                bf16x8 a0 = *(const bf16x8*)&As[(wm + lr + kx) * LDSTR + ks * 32 + lk];
                bf16x8 a1 = *(const bf16x8*)&As[(wm + 16 + lr + kx) * LDSTR + ks * 32 + lk];
                acc[0][0] = __builtin_amdgcn_mfma_f32_16x16x32_bf16(a0, b0r[ks], acc[0][0], 0, 0, 0);
                acc[0][1] = __builtin_amdgcn_mfma_f32_16x16x32_bf16(a0, b1r[ks], acc[0][1], 0, 0, 0);
                acc[1][0] = __builtin_amdgcn_mfma_f32_16x16x32_bf16(a1, b0r[ks], acc[1][0], 0, 0, 0);
                acc[1][1] = __builtin_amdgcn_mfma_f32_16x16x32_bf16(a1, b1r[ks], acc[1][1], 0, 0, 0);
            }
        }
    }
    const int px0 = y * 200 + x0;
#pragma unroll
    for (int i = 0; i < 2; i++) {
#pragma unroll
        for (int j = 0; j < 2; j++) {
#pragma unroll
            for (int r = 0; r < 4; r++) {
                int ml = wm + i * 16 + lkq * 4 + r;
                int nl = wn + j * 16 + lr;
                out[(size_t)(px0 + ml) * OCtot + n0 + nl] = acc[i][j][r];
            }
        }
    }
}

// ---------------- deformable sampling: 1 wave per query ----------------
// v [NVAL][128] bf16, off [nq][512] bf16, att [nq][256] bf16, out [NQ][128] bf16
__global__ __launch_bounds__(256) void deform2_k(
        const u16* __restrict__ v, const u16* __restrict__ off,
        const u16* __restrict__ att, u16* __restrict__ outb,
        int q0, int nq) {
    const int t = threadIdx.x;
    const int wq = t >> 6;
    const int lane = t & 63;
    const int h = lane >> 3;
    const int cl = lane & 7;
    const int qi = blockIdx.x * 4 + wq;
    if (qi >= nq) return;
    const int gq = q0 + qi;
    const float rx = ((gq % 200) + 0.5f) / 200.f;
    const float ry = ((gq / 200) + 0.5f) / 200.f;

    // logits: 32 bf16 -> 16 uints
    const uint* lp = (const uint*)(att + (size_t)qi * 256 + h * 32);
    uint lw[16];
#pragma unroll
    for (int i = 0; i < 16; i++) lw[i] = lp[i];
    float lg[32];
#pragma unroll
    for (int i = 0; i < 16; i++) { lg[2 * i] = blo(lw[i]); lg[2 * i + 1] = bhi(lw[i]); }
    float mx = -1e30f;
#pragma unroll
    for (int i = 0; i < 32; i++) mx = fmaxf(mx, lg[i]);
    float ssum = 0.f;
#pragma unroll
    for (int i = 0; i < 32; i++) { lg[i] = __expf(lg[i] - mx); ssum += lg[i]; }
    const float inv = 1.f / ssum;

    const uint* op = (const uint*)(off + (size_t)qi * 512 + h * 64);  // 32 packed (ox,oy)

    const int HS[4] = {128, 64, 32, 16};
    const int WS[4] = {256, 128, 64, 32};
    const int ST[4] = {0, 32768, 40960, 43008};
    float acc0 = 0.f, acc1 = 0.f;
#pragma unroll
    for (int l = 0; l < 4; l++) {
        const int H = HS[l], W = WS[l];
        const float fW = (float)W, fH = (float)H;
        const u16* vb = v + (size_t)ST[l] * 128 + h * 16 + cl * 2;
#pragma unroll
        for (int p = 0; p < 8; p++) {
            uint pr = op[l * 8 + p];
            float ox = blo(pr), oy = bhi(pr);
            float xx = rx * fW + ox - 0.5f;
            float yy = ry * fH + oy - 0.5f;
            float xf = floorf(xx), yf = floorf(yy);
            int ix = (int)xf, iy = (int)yf;
            float fx = xx - xf, fy = yy - yf;
            float aw = lg[l * 8 + p] * inv;
            int x1 = ix + 1, y1 = iy + 1;
            bool vx0 = (unsigned)ix < (unsigned)W;
            bool vx1 = (unsigned)x1 < (unsigned)W;
            bool vy0 = (unsigned)iy < (unsigned)H;
            bool vy1 = (unsigned)y1 < (unsigned)H;
            int cx0 = min(max(ix, 0), W - 1), cx1 = min(max(x1, 0), W - 1);
            int cy0 = min(max(iy, 0), H - 1), cy1 = min(max(y1, 0), H - 1);
            float w00 = (vx0 && vy0) ? (1.f - fx) * (1.f - fy) * aw : 0.f;
            float w10 = (vx1 && vy0) ? fx * (1.f - fy) * aw : 0.f;
            float w01 = (vx0 && vy1) ? (1.f - fx) * fy * aw : 0.f;
            float w11 = (vx1 && vy1) ? fx * fy * aw : 0.f;
            uint u00 = *(const uint*)(vb + (size_t)(cy0 * W + cx0) * 128);
            uint u10 = *(const uint*)(vb + (size_t)(cy0 * W + cx1) * 128);
            uint u01 = *(const uint*)(vb + (size_t)(cy1 * W + cx0) * 128);
            uint u11 = *(const uint*)(vb + (size_t)(cy1 * W + cx1) * 128);
            acc0 = fmaf(w00, blo(u00), acc0); acc1 = fmaf(w00, bhi(u00), acc1);
            acc0 = fmaf(w10, blo(u10), acc0); acc1 = fmaf(w10, bhi(u10), acc1);
            acc0 = fmaf(w01, blo(u01), acc0); acc1 = fmaf(w01, bhi(u01), acc1);
            acc0 = fmaf(w11, blo(u11), acc0); acc1 = fmaf(w11, bhi(u11), acc1);
        }
    }
    uint o = (uint)f2b(acc0) | ((uint)f2b(acc1) << 16);
    *(uint*)(outb + (size_t)gq * 128 + h * 16 + cl * 2) = o;
}

// ---------------- fused residual + layernorm ----------------
__global__ __launch_bounds__(256) void add_ln_k(
        float* __restrict__ q, const float* __restrict__ a,
        const float* __restrict__ g, const float* __restrict__ b,
        u16* __restrict__ qb) {
    const int row = blockIdx.x * 4 + (threadIdx.x >> 6);
    const int lane = threadIdx.x & 63;
    float s0 = q[(size_t)row * 128 + lane] + a[(size_t)row * 128 + lane];
    float s1 = q[(size_t)row * 128 + 64 + lane] + a[(size_t)row * 128 + 64 + lane];
    float sum = s0 + s1;
    for (int o = 32; o > 0; o >>= 1) sum += __shfl_xor(sum, o, 64);
    float mean = sum * (1.f / 128.f);
    float d0 = s0 - mean, d1 = s1 - mean;
    float vs = d0 * d0 + d1 * d1;
    for (int o = 32; o > 0; o >>= 1) vs += __shfl_xor(vs, o, 64);
    float inv = rsqrtf(vs * (1.f / 128.f) + 1e-5f);
    float o0 = d0 * inv * g[lane] + b[lane];
    float o1 = d1 * inv * g[64 + lane] + b[64 + lane];
    q[(size_t)row * 128 + lane] = o0;
    q[(size_t)row * 128 + 64 + lane] = o1;
    qb[(size_t)row * 128 + lane] = f2b(o0);
    qb[(size_t)row * 128 + 64 + lane] = f2b(o1);
}

// ---------------- pimg fill from qb (128 ch) ----------------
__global__ void fill_pimg_k(const u16* __restrict__ qb, u16* __restrict__ pimg) {
    int i = blockIdx.x * 256 + threadIdx.x;  // over 40000*16 uint4
    if (i >= 640000) return;
    int p = i >> 4, c8 = i & 15;
    int y = p / 200, x = p - y * 200;
    ((uint4*)pimg)[((size_t)(y + 3) * 208 + (x + 3)) * 16 + c8] = ((const uint4*)qb)[i];
}

// ---------------- BN stats + apply ----------------
__global__ __launch_bounds__(256) void bn_stats2_k(const float* __restrict__ x,
                                                   float* __restrict__ acc,
                                                   int cSh, int ppb) {
    const int t = threadIdx.x;
    const int Cp = 1 << cSh;
    const int c = t & (Cp - 1);
    const int sub = t >> cSh;
    const int nsub = 256 >> cSh;
    float s = 0.f, s2 = 0.f;
    const int pbase = blockIdx.x * ppb;
    for (int i = sub; i < ppb; i += nsub) {
        float v = x[(size_t)(pbase + i) * Cp + c];
        s += v; s2 += v * v;
    }
    __shared__ float ls[256], ls2[256];
    ls[t] = s; ls2[t] = s2;
    __syncthreads();
    if (t < Cp) {
        for (int k = 1; k < nsub; k++) { s += ls[t + k * Cp]; s2 += ls2[t + k * Cp]; }
        atomicAdd(&acc[2 * t], s);
        atomicAdd(&acc[2 * t + 1], s2);
    }
}

__global__ void bn_fin_k(const float* __restrict__ acc, float* __restrict__ mv, int C) {
    int t = threadIdx.x;
    if (t >= C) return;
    float m = acc[2 * t] * (1.f / 40000.f);
    float var = acc[2 * t + 1] * (1.f / 40000.f) - m * m;
    mv[2 * t] = m;
    mv[2 * t + 1] = rsqrtf(var + 1e-5f);
}

// apply into padded image layout (interior only; borders pre-zeroed)
__global__ void bn_apply_pad_k(const float* __restrict__ x, const float* __restrict__ mv,
                               const float* __restrict__ g, const float* __restrict__ b,
                               u16* __restrict__ outp, int cSh, int Creal) {
    int i = blockIdx.x * 256 + threadIdx.x;
    int Cp = 1 << cSh;
    if (i >= 40000 * Cp) return;
    int c = i & (Cp - 1);
    int p = i >> cSh;
    int y = p / 200, x_ = p - y * 200;
    float v = 0.f;
    if (c < Creal) v = fmaxf((x[i] - mv[2 * c]) * mv[2 * c + 1] * g[c] + b[c], 0.f);
    outp[((size_t)(y + 3) * 208 + (x_ + 3)) * Cp + c] = f2b(v);
}

// apply into plain [p][Cp] layout (for the final stage feeding the 1x1 head)
__global__ void bn_apply2_k(const float* __restrict__ x, const float* __restrict__ mv,
                            const float* __restrict__ g, const float* __restrict__ b,
                            u16* __restrict__ outb, int cSh, int Creal) {
    int i = blockIdx.x * 256 + threadIdx.x;
    int Cp = 1 << cSh;
    if (i >= 40000 * Cp) return;
    int c = i & (Cp - 1);
    float v = 0.f;
    if (c < Creal) v = fmaxf((x[i] - mv[2 * c]) * mv[2 * c + 1] * g[c] + b[c], 0.f);
    outb[i] = f2b(v);
}

// ---------------- 1x1 obj head ----------------
__global__ void obj_conv_k(const u16* __restrict__ in, const float* __restrict__ w,
                           const float* __restrict__ bias, float* __restrict__ out) {
    int p = blockIdx.x * 256 + threadIdx.x;
    if (p >= 40000) return;
    float xin[48];
#pragma unroll
    for (int c = 0; c < 48; c++) xin[c] = b2f(in[(size_t)p * 64 + c]);
    for (int o = 0; o < NCLS; o++) {
        float acc = bias[o];
#pragma unroll
        for (int c = 0; c < 48; c++) acc += xin[c] * w[o * 48 + c];
        out[(size_t)o * 40000 + p] = acc;
    }
}

extern "C" void kernel_launch(void* const* d_in, const int* in_sizes, int n_in,
                              void* d_out, int out_size, void* d_ws, size_t ws_size,
                              hipStream_t stream) {
    const float* value   = (const float*)d_in[0];
    const float* bev_q   = (const float*)d_in[1];
    const float* bev_pos = (const float*)d_in[2];
    const int*   proj    = (const int*)d_in[3];
    const float* Wv      = (const float*)d_in[4];
    const float* bv      = (const float*)d_in[5];
    const float* Woff    = (const float*)d_in[6];
    const float* boff    = (const float*)d_in[7];
    const float* Wattn   = (const float*)d_in[8];
    const float* battn   = (const float*)d_in[9];
    const float* Wout    = (const float*)d_in[10];
    const float* bout    = (const float*)d_in[11];
    const float* Wf1     = (const float*)d_in[12];
    const float* bf1     = (const float*)d_in[13];
    const float* Wf2     = (const float*)d_in[14];
    const float* bf2     = (const float*)d_in[15];
    const float* ln_g    = (const float*)d_in[16];
    const float* ln_b    = (const float*)d_in[17];
    const float* cw1     = (const float*)d_in[18];
    const float* g1      = (const float*)d_in[19];
    const float* b1      = (const float*)d_in[20];
    const float* cw2     = (const float*)d_in[21];
    const float* g2      = (const float*)d_in[22];
    const float* b2      = (const float*)d_in[23];
    const float* cw3     = (const float*)d_in[24];
    const float* g3      = (const float*)d_in[25];
    const float* b3      = (const float*)d_in[26];
    const float* cw4     = (const float*)d_in[27];
    const float* g4      = (const float*)d_in[28];
    const float* b4      = (const float*)d_in[29];
    const float* objw    = (const float*)d_in[30];
    const float* objb    = (const float*)d_in[31];
    float* out = (float*)d_out;

    float* WSb = (float*)d_ws;
    // encoder-stage layout (float-unit offsets)
    float* q     = WSb + 0;                        // 5,120,000
    u16*   qb    = (u16*)(WSb + 5120000);          // 2,560,000 f
    u16*   qpb   = (u16*)(WSb + 7680000);          // 2,560,000 f
    u16*   valb  = (u16*)(WSb + 10240000);         // 2,785,280 f
    u16*   vbufb = (u16*)(WSb + 13025280);         // 2,785,280 f
    u16*   offb  = (u16*)(WSb + 15810560);         // 2,048,000 f (8000x512 bf16)
    u16*   attb  = (u16*)(WSb + 17858560);         // 1,024,000 f (8000x256 bf16)
    float* tmp   = WSb + 18882560;                 // 5,120,000 f
    u16*   aob   = (u16*)(WSb + 24002560);         // 2,560,000 f
    u16*   hb    = (u16*)(WSb + 26562560);         // 2,560,000 f
    u16*   wenc  = (u16*)(WSb + 29122560);         // 163,840 f
    u16*   wcv   = (u16*)(WSb + 29286400);         // 475,136 f
    float* bnacc = WSb + 29761536;                 // 512
    float* bnmv  = WSb + 29762048;                 // 256
    int*   maxi  = (int*)(WSb + 29762304);

    // conv-stage aliases (encoder buffers dead in sequence)
    u16*   pimg = (u16*)(WSb + 10240000);          // padded 206x208x128 bf16 (over valb)
    float* c1f  = tmp;                             // [40000][128] fp32
    u16*   c1b  = (u16*)(WSb + 13025280);          // padded 206x208x128 (over vbufb)
    float* c2f  = WSb + 0;                         // [40000][64] (over q)
    u16*   c2b  = (u16*)(WSb + 5120000);           // padded 206x208x64 (over qb)
    float* c3f  = WSb + 2560000;                   // [40000][64]
    u16*   c3b  = (u16*)(WSb + 7680000);           // padded 206x208x64 (over qpb)
    float* c4f  = WSb + 0;                         // [40000][64]
    u16*   c4b  = (u16*)(WSb + 15810560);          // [40000][64] plain (over offb)

    const size_t L = 163840; // u16 per encoder layer
    u16* WvT[2]; u16* WoffT[2]; u16* WattnT[2]; u16* WoutT[2]; u16* Wf1T[2]; u16* Wf2T[2];
    for (int l = 0; l < 2; l++) {
        u16* base = wenc + l * L;
        WvT[l]    = base;
        WoffT[l]  = base + 16384;
        WattnT[l] = base + 81920;
        WoutT[l]  = base + 114688;
        Wf1T[l]   = base + 131072;
        Wf2T[l]   = base + 147456;
    }
    u16* w1T = wcv;                 // [49][128][128]
    u16* w2T = wcv + 802816;        // [9][64][128]
    u16* w3T = wcv + 876544;        // [9][64][64]
    u16* w4T = wcv + 913408;        // [9][64][64]

    // ---- mask ----
    hipMemsetAsync(maxi, 0, sizeof(int), stream);
    reduce_max_int<<<157, 256, 0, stream>>>(proj, maxi);
    write_mask<<<157, 256, 0, stream>>>(proj, maxi, out + 840000);

    // ---- weight packing ----
    pack_enc_k<<<1280, 256, 0, stream>>>(Wv, Woff, Wattn, Wout, Wf1, Wf2, wenc);
    pack_cw_k<<<3136, 256, 0, stream>>>(cw1, w1T, 128, 128, 7, 128, 128);
    pack_cw_k<<<288, 256, 0, stream>>>(cw2, w2T, 64, 128, 3, 64, 128);
    pack_cw_k<<<144, 256, 0, stream>>>(cw3, w3T, 48, 64, 3, 64, 64);
    pack_cw_k<<<144, 256, 0, stream>>>(cw4, w4T, 48, 48, 3, 64, 64);
    cvt_b_k<<<2720, 256, 0, stream>>>(value, valb, NVAL * 128 / 8);

    // ---- encoder ----
    hipMemcpyAsync(q, bev_q, (size_t)NQ * EDIM * sizeof(float),
                   hipMemcpyDeviceToDevice, stream);
    for (int l = 0; l < 2; l++) {
        gemm_mfma_k<<<dim3(680, 2), 256, 0, stream>>>(
            valb, WvT[l], bv + (size_t)l * 128, nullptr, vbufb, 128, 0);
        add2b_k<<<2500, 256, 0, stream>>>(q, bev_pos, qpb, NQ * 128 / 8);
        for (int cidx = 0; cidx < 5; cidx++) {
            int qs = cidx * 8000;
            gemm_mfma_k<<<dim3(125, 8), 256, 0, stream>>>(
                qpb + (size_t)qs * 128, WoffT[l], boff + (size_t)l * 512,
                nullptr, offb, 512, 0);
            gemm_mfma_k<<<dim3(125, 4), 256, 0, stream>>>(
                qpb + (size_t)qs * 128, WattnT[l], battn + (size_t)l * 256,
                nullptr, attb, 256, 0);
            deform2_k<<<2000, 256, 0, stream>>>(vbufb, offb, attb, aob, qs, 8000);
        }
        gemm_mfma_k<<<dim3(625, 2), 256, 0, stream>>>(
            aob, WoutT[l], bout + (size_t)l * 128, tmp, nullptr, 128, 0);
        add_ln_k<<<10000, 256, 0, stream>>>(q, tmp, ln_g + (size_t)(l * 2 + 0) * 128,
                                            ln_b + (size_t)(l * 2 + 0) * 128, qb);
        gemm_mfma_k<<<dim3(625, 2), 256, 0, stream>>>(
            qb, Wf1T[l], bf1 + (size_t)l * 128, nullptr, hb, 128, 1);
        gemm_mfma_k<<<dim3(625, 2), 256, 0, stream>>>(
            hb, Wf2T[l], bf2 + (size_t)l * 128, tmp, nullptr, 128, 0);
        add_ln_k<<<10000, 256, 0, stream>>>(q, tmp, ln_g + (size_t)(l * 2 + 1) * 128,
                                            ln_b + (size_t)(l * 2 + 1) * 128, qb);
    }

    // ---- conv head ----
    hipMemsetAsync(pimg, 0, (size_t)206 * 208 * 128 * 2, stream);
    fill_pimg_k<<<2500, 256, 0, stream>>>(qb, pimg);

    conv2_mfma_k<7, 128><<<dim3(800, 2), 256, 0, stream>>>(pimg, w1T, c1f, 128);
    hipMemsetAsync(bnacc, 0, 512 * sizeof(float), stream);
    bn_stats2_k<<<125, 256, 0, stream>>>(c1f, bnacc, 7, 320);
    bn_fin_k<<<1, 128, 0, stream>>>(bnacc, bnmv, 128);
    hipMemsetAsync(c1b, 0, (size_t)206 * 208 * 128 * 2, stream);
    bn_apply_pad_k<<<20000, 256, 0, stream>>>(c1f, bnmv, g1, b1, c1b, 7, 128);

    conv2_mfma_k<3, 128><<<dim3(800, 1), 256, 0, stream>>>(c1b, w2T, c2f, 64);
    hipMemsetAsync(bnacc, 0, 512 * sizeof(float), stream);
    bn_stats2_k<<<125, 256, 0, stream>>>(c2f, bnacc, 6, 320);
    bn_fin_k<<<1, 64, 0, stream>>>(bnacc, bnmv, 64);
    hipMemsetAsync(c2b, 0, (size_t)206 * 208 * 64 * 2, stream);
    bn_apply_pad_k<<<10000, 256, 0, stream>>>(c2f, bnmv, g2, b2, c2b, 6, 64);

    conv2_mfma_k<3, 64><<<dim3(800, 1), 256, 0, stream>>>(c2b, w3T, c3f, 64);
    hipMemsetAsync(bnacc, 0, 512 * sizeof(float), stream);
    bn_stats2_k<<<125, 256, 0, stream>>>(c3f, bnacc, 6, 320);
    bn_fin_k<<<1, 48, 0, stream>>>(bnacc, bnmv, 48);
    hipMemsetAsync(c3b, 0, (size_t)206 * 208 * 64 * 2, stream);
    bn_apply_pad_k<<<10000, 256, 0, stream>>>(c3f, bnmv, g3, b3, c3b, 6, 48);

    conv2_mfma_k<3, 64><<<dim3(800, 1), 256, 0, stream>>>(c3b, w4T, c4f, 64);
    hipMemsetAsync(bnacc, 0, 512 * sizeof(float), stream);
    bn_stats2_k<<<125, 256, 0, stream>>>(c4f, bnacc, 6, 320);
    bn_fin_k<<<1, 48, 0, stream>>>(bnacc, bnmv, 48);
    bn_apply2_k<<<10000, 256, 0, stream>>>(c4f, bnmv, g4, b4, c4b, 6, 48);

    obj_conv_k<<<157, 256, 0, stream>>>(c4b, objw, objb, out);
}

// Round 4
// 1141.136 us; speedup vs baseline: 3.2105x; 1.2047x over previous
//
#include <hip/hip_runtime.h>
#include <cstdint>
#include <cstddef>

#define NQ 40000
#define EDIM 128
#define NVAL 43520
#define NCLS 21

typedef unsigned short u16;
typedef unsigned int uint;
typedef short bf16x8 __attribute__((ext_vector_type(8)));
typedef float f32x4 __attribute__((ext_vector_type(4)));

__device__ inline u16 f2b(float f) {
    unsigned u = __float_as_uint(f);
    unsigned r = u + 0x7FFF + ((u >> 16) & 1);
    return (u16)(r >> 16);
}
__device__ inline float b2f(u16 v) {
    unsigned u = ((unsigned)v) << 16;
    return __uint_as_float(u);
}
__device__ inline float blo(uint u) { return __uint_as_float(u << 16); }
__device__ inline float bhi(uint u) { return __uint_as_float(u & 0xFFFF0000u); }

// ---------------- mask ----------------
__global__ void reduce_max_int(const int* __restrict__ idx, int* __restrict__ mx) {
    int i = blockIdx.x * 256 + threadIdx.x;
    int v = (i < NQ) ? idx[i] : 0;
    for (int o = 32; o > 0; o >>= 1) v = max(v, __shfl_xor(v, o, 64));
    if ((threadIdx.x & 63) == 0) atomicMax(mx, v);
}

__global__ void write_mask(const int* __restrict__ idx, const int* __restrict__ mx,
                           float* __restrict__ out) {
    int i = blockIdx.x * 256 + threadIdx.x;
    if (i >= NQ) return;
    out[i] = (idx[i] < *mx) ? 1.0f : 0.0f;
}

// ---------------- conversions / packing ----------------
__global__ void cvt_b_k(const float* __restrict__ src, u16* __restrict__ dst, int n8) {
    int i = blockIdx.x * 256 + threadIdx.x;
    if (i >= n8) return;
    const float4 a = ((const float4*)src)[i * 2];
    const float4 b = ((const float4*)src)[i * 2 + 1];
    u16 o[8] = {f2b(a.x), f2b(a.y), f2b(a.z), f2b(a.w), f2b(b.x), f2b(b.y), f2b(b.z), f2b(b.w)};
    ((uint4*)dst)[i] = *(const uint4*)o;
}

__global__ void add2b_k(const float* __restrict__ a, const float* __restrict__ b,
                        u16* __restrict__ c, int n8) {
    int i = blockIdx.x * 256 + threadIdx.x;
    if (i >= n8) return;
    const float4 a0 = ((const float4*)a)[i * 2], a1 = ((const float4*)a)[i * 2 + 1];
    const float4 b0 = ((const float4*)b)[i * 2], b1 = ((const float4*)b)[i * 2 + 1];
    u16 o[8] = {f2b(a0.x + b0.x), f2b(a0.y + b0.y), f2b(a0.z + b0.z), f2b(a0.w + b0.w),
                f2b(a1.x + b1.x), f2b(a1.y + b1.y), f2b(a1.z + b1.z), f2b(a1.w + b1.w)};
    ((uint4*)c)[i] = *(const uint4*)o;
}

// fused encoder weight pack: all 6 matrices x 2 layers -> [n][128] bf16
__global__ void pack_enc_k(const float* __restrict__ Wv, const float* __restrict__ Woff,
                           const float* __restrict__ Wattn, const float* __restrict__ Wout,
                           const float* __restrict__ Wf1, const float* __restrict__ Wf2,
                           u16* __restrict__ dst) {
    int i = blockIdx.x * 256 + threadIdx.x;
    if (i >= 327680) return;
    int l = i / 163840, r = i % 163840;
    int k = r / 1280, col = r % 1280;
    const float* src; int N; int n; u16* d;
    u16* base = dst + (size_t)l * 163840;
    if (col < 128)       { src = Wv    + (size_t)l * 16384; N = 128; n = col;        d = base;          }
    else if (col < 640)  { src = Woff  + (size_t)l * 65536; N = 512; n = col - 128;  d = base + 16384;  }
    else if (col < 896)  { src = Wattn + (size_t)l * 32768; N = 256; n = col - 640;  d = base + 81920;  }
    else if (col < 1024) { src = Wout  + (size_t)l * 16384; N = 128; n = col - 896;  d = base + 114688; }
    else if (col < 1152) { src = Wf1   + (size_t)l * 16384; N = 128; n = col - 1024; d = base + 131072; }
    else                 { src = Wf2   + (size_t)l * 16384; N = 128; n = col - 1152; d = base + 147456; }
    d[(size_t)n * 128 + k] = f2b(src[(size_t)k * N + n]);
}

__global__ void pack_bias_k(const float* __restrict__ boff, const float* __restrict__ battn,
                            float* __restrict__ dst) {
    int i = blockIdx.x * 256 + threadIdx.x;
    if (i >= 1536) return;
    int l = i / 768, r = i % 768;
    dst[i] = (r < 512) ? boff[(size_t)l * 512 + r] : battn[(size_t)l * 256 + r - 512];
}

// cw [OC][IC][KS][KS] fp32 -> wT [KS*KS][OCp][ICp] bf16 (zero-padded)
__global__ void pack_cw_k(const float* __restrict__ w, u16* __restrict__ wT,
                          int OC, int IC, int KS, int OCp, int ICp) {
    int i = blockIdx.x * 256 + threadIdx.x;
    int tot = KS * KS * OCp * ICp;
    if (i >= tot) return;
    int ic = i % ICp; int r = i / ICp;
    int oc = r % OCp; int tap = r / OCp;
    int ky = tap / KS, kx = tap % KS;
    float v = 0.f;
    if (oc < OC && ic < IC)
        v = w[(((size_t)oc * IC + ic) * KS + ky) * KS + kx];
    wT[i] = f2b(v);
}

// ---------------- MFMA GEMM: C[M][N] = A[M][128] @ BT^T + bias ----------------
__global__ __launch_bounds__(256) void gemm_mfma_k(
        const u16* __restrict__ A, const u16* __restrict__ BT,
        const float* __restrict__ bias, float* __restrict__ Cf,
        u16* __restrict__ Cb, int N, int relu) {
    __shared__ u16 As[64 * 136];
    __shared__ u16 Bs[64 * 136];
    const int m0 = blockIdx.x * 64, n0 = blockIdx.y * 64;
    const int t = threadIdx.x;
#pragma unroll
    for (int ci = t; ci < 1024; ci += 256) {
        int r = ci >> 4, c = ci & 15;
        *(uint4*)&As[r * 136 + c * 8] = *(const uint4*)&A[(size_t)(m0 + r) * 128 + c * 8];
        *(uint4*)&Bs[r * 136 + c * 8] = *(const uint4*)&BT[(size_t)(n0 + r) * 128 + c * 8];
    }
    __syncthreads();
    const int wave = t >> 6, lane = t & 63;
    const int wm = (wave & 1) * 32, wn = (wave >> 1) * 32;
    const int lr = lane & 15, lk = (lane >> 4) * 8;
    f32x4 acc[2][2] = {};
#pragma unroll
    for (int ks = 0; ks < 4; ks++) {
        bf16x8 a0 = *(const bf16x8*)&As[(wm + lr) * 136 + ks * 32 + lk];
        bf16x8 a1 = *(const bf16x8*)&As[(wm + 16 + lr) * 136 + ks * 32 + lk];
        bf16x8 b0 = *(const bf16x8*)&Bs[(wn + lr) * 136 + ks * 32 + lk];
        bf16x8 b1 = *(const bf16x8*)&Bs[(wn + 16 + lr) * 136 + ks * 32 + lk];
        acc[0][0] = __builtin_amdgcn_mfma_f32_16x16x32_bf16(a0, b0, acc[0][0], 0, 0, 0);
        acc[0][1] = __builtin_amdgcn_mfma_f32_16x16x32_bf16(a0, b1, acc[0][1], 0, 0, 0);
        acc[1][0] = __builtin_amdgcn_mfma_f32_16x16x32_bf16(a1, b0, acc[1][0], 0, 0, 0);
        acc[1][1] = __builtin_amdgcn_mfma_f32_16x16x32_bf16(a1, b1, acc[1][1], 0, 0, 0);
    }
    float bj0 = bias[n0 + wn + lr];
    float bj1 = bias[n0 + wn + 16 + lr];
#pragma unroll
    for (int i = 0; i < 2; i++) {
#pragma unroll
        for (int j = 0; j < 2; j++) {
            float bb = j ? bj1 : bj0;
#pragma unroll
            for (int r = 0; r < 4; r++) {
                int ml = wm + i * 16 + (lane >> 4) * 4 + r;
                int nl = wn + j * 16 + lr;
                float v = acc[i][j][r] + bb;
                if (relu) v = fmaxf(v, 0.f);
                size_t o = (size_t)(m0 + ml) * N + n0 + nl;
                if (Cf) Cf[o] = v;
                if (Cb) Cb[o] = f2b(v);
            }
        }
    }
}

// ---------------- conv: 128px (2 rows) x 64 OC, double-buffered register B ----------------
// pimg: padded [206][208][ICP] bf16 (3px frame, zeroed)
// wT: [KS*KS][OCtot][ICP] bf16 ; out: [40000][OCtot] fp32
template <int KS, int ICP>
__global__ __launch_bounds__(256) void conv3_mfma_k(
        const u16* __restrict__ pimg, const u16* __restrict__ wT,
        float* __restrict__ out, int OCtot) {
    constexpr int PAD = KS / 2;
    constexpr int WIN = 64 + KS - 1;
    constexpr int LDSTR = ICP + 8;
    constexpr int KSTEPS = ICP / 32;
    constexpr int CHUNKS = 2 * WIN * (ICP / 8);
    __shared__ u16 As[2 * WIN * LDSTR];
    const int bx = blockIdx.x;
    const int y = (bx >> 2) * 2;           // two output rows y, y+1
    const int xc = bx & 3;
    const int x0 = (xc == 3) ? 136 : xc * 64;
    const int n0 = blockIdx.y * 64;
    const int t = threadIdx.x;
    const int wave = t >> 6, lane = t & 63;
    const int rowsel = wave >> 1;          // which output row
    const int wn = (wave & 1) * 32;
    const int lr = lane & 15, lkq = lane >> 4, lk = lkq * 8;
    f32x4 acc[4][2] = {};
    bf16x8 bbA[2][KSTEPS], bbB[2][KSTEPS];

    auto loadB = [&](int tap, bf16x8 (&bb)[2][KSTEPS]) {
        const u16* wb = wT + ((size_t)tap * OCtot + n0) * ICP;
#pragma unroll
        for (int ks = 0; ks < KSTEPS; ks++) {
            bb[0][ks] = *(const bf16x8*)&wb[(size_t)(wn + lr) * ICP + ks * 32 + lk];
            bb[1][ks] = *(const bf16x8*)&wb[(size_t)(wn + 16 + lr) * ICP + ks * 32 + lk];
        }
    };

    for (int ky = 0; ky < KS; ky++) {
        __syncthreads();
        for (int ci = t; ci < CHUNKS; ci += 256) {
            int w2 = ci / (WIN * (ICP / 8));
            int rem = ci - w2 * WIN * (ICP / 8);
            int r = rem / (ICP / 8), c = rem - r * (ICP / 8);
            const u16* src = pimg +
                (((size_t)(y + w2 + ky + 3 - PAD)) * 208 + (x0 + 3 - PAD)) * ICP;
            *(uint4*)&As[(w2 * WIN + r) * LDSTR + c * 8] = *(const uint4*)&src[(size_t)r * ICP + c * 8];
        }
        __syncthreads();
        loadB(ky * KS, bbA);
        const u16* asb = &As[rowsel * WIN * LDSTR];
#pragma unroll
        for (int kx = 0; kx < KS; kx++) {
            if (kx + 1 < KS) {
                if (kx & 1) loadB(ky * KS + kx + 1, bbA);
                else        loadB(ky * KS + kx + 1, bbB);
            }
#pragma unroll
            for (int ks = 0; ks < KSTEPS; ks++) {
                bf16x8 a0 = *(const bf16x8*)&asb[(lr + kx) * LDSTR + ks * 32 + lk];
                bf16x8 a1 = *(const bf16x8*)&asb[(lr + 16 + kx) * LDSTR + ks * 32 + lk];
                bf16x8 a2 = *(const bf16x8*)&asb[(lr + 32 + kx) * LDSTR + ks * 32 + lk];
                bf16x8 a3 = *(const bf16x8*)&asb[(lr + 48 + kx) * LDSTR + ks * 32 + lk];
#pragma unroll
                for (int j = 0; j < 2; j++) {
                    bf16x8 bj = (kx & 1) ? bbB[j][ks] : bbA[j][ks];
                    acc[0][j] = __builtin_amdgcn_mfma_f32_16x16x32_bf16(a0, bj, acc[0][j], 0, 0, 0);
                    acc[1][j] = __builtin_amdgcn_mfma_f32_16x16x32_bf16(a1, bj, acc[1][j], 0, 0, 0);
                    acc[2][j] = __builtin_amdgcn_mfma_f32_16x16x32_bf16(a2, bj, acc[2][j], 0, 0, 0);
                    acc[3][j] = __builtin_amdgcn_mfma_f32_16x16x32_bf16(a3, bj, acc[3][j], 0, 0, 0);
                }
            }
        }
    }
    const int px0 = (y + rowsel) * 200 + x0;
#pragma unroll
    for (int i = 0; i < 4; i++) {
#pragma unroll
        for (int j = 0; j < 2; j++) {
#pragma unroll
            for (int r = 0; r < 4; r++) {
                int ml = i * 16 + lkq * 4 + r;
                int nl = wn + j * 16 + lr;
                out[(size_t)(px0 + ml) * OCtot + n0 + nl] = acc[i][j][r];
            }
        }
    }
}

// ---------------- deformable sampling: 1 wave per query, fused off+attn input ----------------
// v [NVAL][128] bf16, oa [nq][768] bf16 (512 offsets + 256 logits), out [NQ][128] bf16
__global__ __launch_bounds__(256) void deform2_k(
        const u16* __restrict__ v, const u16* __restrict__ oa,
        u16* __restrict__ outb, int q0, int nq) {
    const int t = threadIdx.x;
    const int wq = t >> 6;
    const int lane = t & 63;
    const int h = lane >> 3;
    const int cl = lane & 7;
    const int qi = blockIdx.x * 4 + wq;
    if (qi >= nq) return;
    const int gq = q0 + qi;
    const float rx = ((gq % 200) + 0.5f) / 200.f;
    const float ry = ((gq / 200) + 0.5f) / 200.f;

    const uint* lp = (const uint*)(oa + (size_t)qi * 768 + 512 + h * 32);
    uint lw[16];
#pragma unroll
    for (int i = 0; i < 16; i++) lw[i] = lp[i];
    float lg[32];
#pragma unroll
    for (int i = 0; i < 16; i++) { lg[2 * i] = blo(lw[i]); lg[2 * i + 1] = bhi(lw[i]); }
    float mx = -1e30f;
#pragma unroll
    for (int i = 0; i < 32; i++) mx = fmaxf(mx, lg[i]);
    float ssum = 0.f;
#pragma unroll
    for (int i = 0; i < 32; i++) { lg[i] = __expf(lg[i] - mx); ssum += lg[i]; }
    const float inv = 1.f / ssum;

    const uint* op = (const uint*)(oa + (size_t)qi * 768 + h * 64);

    const int HS[4] = {128, 64, 32, 16};
    const int WS[4] = {256, 128, 64, 32};
    const int ST[4] = {0, 32768, 40960, 43008};
    float acc0 = 0.f, acc1 = 0.f;
#pragma unroll
    for (int l = 0; l < 4; l++) {
        const int H = HS[l], W = WS[l];
        const float fW = (float)W, fH = (float)H;
        const u16* vb = v + (size_t)ST[l] * 128 + h * 16 + cl * 2;
#pragma unroll
        for (int p = 0; p < 8; p++) {
            uint pr = op[l * 8 + p];
            float ox = blo(pr), oy = bhi(pr);
            float xx = rx * fW + ox - 0.5f;
            float yy = ry * fH + oy - 0.5f;
            float xf = floorf(xx), yf = floorf(yy);
            int ix = (int)xf, iy = (int)yf;
            float fx = xx - xf, fy = yy - yf;
            float aw = lg[l * 8 + p] * inv;
            int x1 = ix + 1, y1 = iy + 1;
            bool vx0 = (unsigned)ix < (unsigned)W;
            bool vx1 = (unsigned)x1 < (unsigned)W;
            bool vy0 = (unsigned)iy < (unsigned)H;
            bool vy1 = (unsigned)y1 < (unsigned)H;
            int cx0 = min(max(ix, 0), W - 1), cx1 = min(max(x1, 0), W - 1);
            int cy0 = min(max(iy, 0), H - 1), cy1 = min(max(y1, 0), H - 1);
            float w00 = (vx0 && vy0) ? (1.f - fx) * (1.f - fy) * aw : 0.f;
            float w10 = (vx1 && vy0) ? fx * (1.f - fy) * aw : 0.f;
            float w01 = (vx0 && vy1) ? (1.f - fx) * fy * aw : 0.f;
            float w11 = (vx1 && vy1) ? fx * fy * aw : 0.f;
            uint u00 = *(const uint*)(vb + (size_t)(cy0 * W + cx0) * 128);
            uint u10 = *(const uint*)(vb + (size_t)(cy0 * W + cx1) * 128);
            uint u01 = *(const uint*)(vb + (size_t)(cy1 * W + cx0) * 128);
            uint u11 = *(const uint*)(vb + (size_t)(cy1 * W + cx1) * 128);
            acc0 = fmaf(w00, blo(u00), acc0); acc1 = fmaf(w00, bhi(u00), acc1);
            acc0 = fmaf(w10, blo(u10), acc0); acc1 = fmaf(w10, bhi(u10), acc1);
            acc0 = fmaf(w01, blo(u01), acc0); acc1 = fmaf(w01, bhi(u01), acc1);
            acc0 = fmaf(w11, blo(u11), acc0); acc1 = fmaf(w11, bhi(u11), acc1);
        }
    }
    uint o = (uint)f2b(acc0) | ((uint)f2b(acc1) << 16);
    *(uint*)(outb + (size_t)gq * 128 + h * 16 + cl * 2) = o;
}

// ---------------- fused residual + layernorm ----------------
__global__ __launch_bounds__(256) void add_ln_k(
        float* __restrict__ q, const float* __restrict__ a,
        const float* __restrict__ g, const float* __restrict__ b,
        u16* __restrict__ qb) {
    const int row = blockIdx.x * 4 + (threadIdx.x >> 6);
    const int lane = threadIdx.x & 63;
    float s0 = q[(size_t)row * 128 + lane] + a[(size_t)row * 128 + lane];
    float s1 = q[(size_t)row * 128 + 64 + lane] + a[(size_t)row * 128 + 64 + lane];
    float sum = s0 + s1;
    for (int o = 32; o > 0; o >>= 1) sum += __shfl_xor(sum, o, 64);
    float mean = sum * (1.f / 128.f);
    float d0 = s0 - mean, d1 = s1 - mean;
    float vs = d0 * d0 + d1 * d1;
    for (int o = 32; o > 0; o >>= 1) vs += __shfl_xor(vs, o, 64);
    float inv = rsqrtf(vs * (1.f / 128.f) + 1e-5f);
    float o0 = d0 * inv * g[lane] + b[lane];
    float o1 = d1 * inv * g[64 + lane] + b[64 + lane];
    q[(size_t)row * 128 + lane] = o0;
    q[(size_t)row * 128 + 64 + lane] = o1;
    qb[(size_t)row * 128 + lane] = f2b(o0);
    qb[(size_t)row * 128 + 64 + lane] = f2b(o1);
}

// ---------------- pimg fill from qb (128 ch) ----------------
__global__ void fill_pimg_k(const u16* __restrict__ qb, u16* __restrict__ pimg) {
    int i = blockIdx.x * 256 + threadIdx.x;
    if (i >= 640000) return;
    int p = i >> 4, c8 = i & 15;
    int y = p / 200, x = p - y * 200;
    ((uint4*)pimg)[((size_t)(y + 3) * 208 + (x + 3)) * 16 + c8] = ((const uint4*)qb)[i];
}

// ---------------- BN stats + apply ----------------
__global__ __launch_bounds__(256) void bn_stats2_k(const float* __restrict__ x,
                                                   float* __restrict__ acc,
                                                   int cSh, int ppb) {
    const int t = threadIdx.x;
    const int Cp = 1 << cSh;
    const int c = t & (Cp - 1);
    const int sub = t >> cSh;
    const int nsub = 256 >> cSh;
    float s = 0.f, s2 = 0.f;
    const int pbase = blockIdx.x * ppb;
    for (int i = sub; i < ppb; i += nsub) {
        float v = x[(size_t)(pbase + i) * Cp + c];
        s += v; s2 += v * v;
    }
    __shared__ float ls[256], ls2[256];
    ls[t] = s; ls2[t] = s2;
    __syncthreads();
    if (t < Cp) {
        for (int k = 1; k < nsub; k++) { s += ls[t + k * Cp]; s2 += ls2[t + k * Cp]; }
        atomicAdd(&acc[2 * t], s);
        atomicAdd(&acc[2 * t + 1], s2);
    }
}

__global__ void bn_fin_k(const float* __restrict__ acc, float* __restrict__ mv, int C) {
    int t = threadIdx.x;
    if (t >= C) return;
    float m = acc[2 * t] * (1.f / 40000.f);
    float var = acc[2 * t + 1] * (1.f / 40000.f) - m * m;
    mv[2 * t] = m;
    mv[2 * t + 1] = rsqrtf(var + 1e-5f);
}

__global__ void bn_apply_pad_k(const float* __restrict__ x, const float* __restrict__ mv,
                               const float* __restrict__ g, const float* __restrict__ b,
                               u16* __restrict__ outp, int cSh, int Creal) {
    int i = blockIdx.x * 256 + threadIdx.x;
    int Cp = 1 << cSh;
    if (i >= 40000 * Cp) return;
    int c = i & (Cp - 1);
    int p = i >> cSh;
    int y = p / 200, x_ = p - y * 200;
    float v = 0.f;
    if (c < Creal) v = fmaxf((x[i] - mv[2 * c]) * mv[2 * c + 1] * g[c] + b[c], 0.f);
    outp[((size_t)(y + 3) * 208 + (x_ + 3)) * Cp + c] = f2b(v);
}

__global__ void bn_apply2_k(const float* __restrict__ x, const float* __restrict__ mv,
                            const float* __restrict__ g, const float* __restrict__ b,
                            u16* __restrict__ outb, int cSh, int Creal) {
    int i = blockIdx.x * 256 + threadIdx.x;
    int Cp = 1 << cSh;
    if (i >= 40000 * Cp) return;
    int c = i & (Cp - 1);
    float v = 0.f;
    if (c < Creal) v = fmaxf((x[i] - mv[2 * c]) * mv[2 * c + 1] * g[c] + b[c], 0.f);
    outb[i] = f2b(v);
}

// ---------------- 1x1 obj head ----------------
__global__ void obj_conv_k(const u16* __restrict__ in, const float* __restrict__ w,
                           const float* __restrict__ bias, float* __restrict__ out) {
    int p = blockIdx.x * 256 + threadIdx.x;
    if (p >= 40000) return;
    float xin[48];
#pragma unroll
    for (int c = 0; c < 48; c++) xin[c] = b2f(in[(size_t)p * 64 + c]);
    for (int o = 0; o < NCLS; o++) {
        float acc = bias[o];
#pragma unroll
        for (int c = 0; c < 48; c++) acc += xin[c] * w[o * 48 + c];
        out[(size_t)o * 40000 + p] = acc;
    }
}

extern "C" void kernel_launch(void* const* d_in, const int* in_sizes, int n_in,
                              void* d_out, int out_size, void* d_ws, size_t ws_size,
                              hipStream_t stream) {
    const float* value   = (const float*)d_in[0];
    const float* bev_q   = (const float*)d_in[1];
    const float* bev_pos = (const float*)d_in[2];
    const int*   proj    = (const int*)d_in[3];
    const float* Wv      = (const float*)d_in[4];
    const float* bv      = (const float*)d_in[5];
    const float* Woff    = (const float*)d_in[6];
    const float* boff    = (const float*)d_in[7];
    const float* Wattn   = (const float*)d_in[8];
    const float* battn   = (const float*)d_in[9];
    const float* Wout    = (const float*)d_in[10];
    const float* bout    = (const float*)d_in[11];
    const float* Wf1     = (const float*)d_in[12];
    const float* bf1     = (const float*)d_in[13];
    const float* Wf2     = (const float*)d_in[14];
    const float* bf2     = (const float*)d_in[15];
    const float* ln_g    = (const float*)d_in[16];
    const float* ln_b    = (const float*)d_in[17];
    const float* cw1     = (const float*)d_in[18];
    const float* g1      = (const float*)d_in[19];
    const float* b1      = (const float*)d_in[20];
    const float* cw2     = (const float*)d_in[21];
    const float* g2      = (const float*)d_in[22];
    const float* b2      = (const float*)d_in[23];
    const float* cw3     = (const float*)d_in[24];
    const float* g3      = (const float*)d_in[25];
    const float* b3      = (const float*)d_in[26];
    const float* cw4     = (const float*)d_in[27];
    const float* g4      = (const float*)d_in[28];
    const float* b4      = (const float*)d_in[29];
    const float* objw    = (const float*)d_in[30];
    const float* objb    = (const float*)d_in[31];
    float* out = (float*)d_out;

    float* WSb = (float*)d_ws;
    // encoder-stage layout (float-unit offsets)
    float* q     = WSb + 0;                        // 5,120,000
    u16*   qb    = (u16*)(WSb + 5120000);          // 2,560,000 f
    u16*   qpb   = (u16*)(WSb + 7680000);          // 2,560,000 f
    u16*   valb  = (u16*)(WSb + 10240000);         // 2,785,280 f
    u16*   vbufb = (u16*)(WSb + 13025280);         // 2,785,280 f
    u16*   fb    = (u16*)(WSb + 15810560);         // fused off+attn [20032][768] bf16 = 7,692,288 f
    float* tmp   = WSb + 18882560;                 // 5,120,000 f (used after sampling only)
    u16*   aob   = (u16*)(WSb + 24002560);         // 2,560,000 f
    u16*   hb    = (u16*)(WSb + 26562560);         // 2,560,000 f
    u16*   wenc  = (u16*)(WSb + 29122560);         // 163,840 f
    u16*   wcv   = (u16*)(WSb + 29286400);         // 475,136 f
    float* bnacc = WSb + 29761536;                 // 512
    float* bnmv  = WSb + 29762048;                 // 256
    int*   maxi  = (int*)(WSb + 29762304);
    float* fbias = WSb + 29762308;                 // 1536

    // conv-stage aliases
    u16*   pimg = (u16*)(WSb + 10240000);          // padded 206x208x128 (over valb)
    float* c1f  = tmp;
    u16*   c1b  = (u16*)(WSb + 13025280);          // padded 206x208x128 (over vbufb)
    float* c2f  = WSb + 0;
    u16*   c2b  = (u16*)(WSb + 5120000);           // padded 206x208x64 (over qb)
    float* c3f  = WSb + 2560000;
    u16*   c3b  = (u16*)(WSb + 7680000);           // padded 206x208x64 (over qpb)
    float* c4f  = WSb + 0;
    u16*   c4b  = (u16*)(WSb + 15810560);          // [40000][64] plain (over fb)

    const size_t L = 163840;
    u16* WvT[2]; u16* WoffT[2]; u16* WoutT[2]; u16* Wf1T[2]; u16* Wf2T[2];
    for (int l = 0; l < 2; l++) {
        u16* base = wenc + l * L;
        WvT[l]    = base;
        WoffT[l]  = base + 16384;   // rows 0..511 = Woff, 512..767 = Wattn (adjacent)
        WoutT[l]  = base + 114688;
        Wf1T[l]   = base + 131072;
        Wf2T[l]   = base + 147456;
    }
    u16* w1T = wcv;
    u16* w2T = wcv + 802816;
    u16* w3T = wcv + 876544;
    u16* w4T = wcv + 913408;

    // ---- mask ----
    hipMemsetAsync(maxi, 0, sizeof(int), stream);
    reduce_max_int<<<157, 256, 0, stream>>>(proj, maxi);
    write_mask<<<157, 256, 0, stream>>>(proj, maxi, out + 840000);

    // ---- weight packing ----
    pack_enc_k<<<1280, 256, 0, stream>>>(Wv, Woff, Wattn, Wout, Wf1, Wf2, wenc);
    pack_bias_k<<<6, 256, 0, stream>>>(boff, battn, fbias);
    pack_cw_k<<<3136, 256, 0, stream>>>(cw1, w1T, 128, 128, 7, 128, 128);
    pack_cw_k<<<288, 256, 0, stream>>>(cw2, w2T, 64, 128, 3, 64, 128);
    pack_cw_k<<<144, 256, 0, stream>>>(cw3, w3T, 48, 64, 3, 64, 64);
    pack_cw_k<<<144, 256, 0, stream>>>(cw4, w4T, 48, 48, 3, 64, 64);
    cvt_b_k<<<2720, 256, 0, stream>>>(value, valb, NVAL * 128 / 8);

    // ---- encoder ----
    hipMemcpyAsync(q, bev_q, (size_t)NQ * EDIM * sizeof(float),
                   hipMemcpyDeviceToDevice, stream);
    const int CH0 = 19968, CH1 = 20032;
    for (int l = 0; l < 2; l++) {
        gemm_mfma_k<<<dim3(680, 2), 256, 0, stream>>>(
            valb, WvT[l], bv + (size_t)l * 128, nullptr, vbufb, 128, 0);
        add2b_k<<<2500, 256, 0, stream>>>(q, bev_pos, qpb, NQ * 128 / 8);
        for (int cidx = 0; cidx < 2; cidx++) {
            int qs = cidx ? CH0 : 0;
            int nq = cidx ? CH1 : CH0;
            gemm_mfma_k<<<dim3(nq / 64, 12), 256, 0, stream>>>(
                qpb + (size_t)qs * 128, WoffT[l], fbias + (size_t)l * 768,
                nullptr, fb, 768, 0);
            deform2_k<<<nq / 4, 256, 0, stream>>>(vbufb, fb, aob, qs, nq);
        }
        gemm_mfma_k<<<dim3(625, 2), 256, 0, stream>>>(
            aob, WoutT[l], bout + (size_t)l * 128, tmp, nullptr, 128, 0);
        add_ln_k<<<10000, 256, 0, stream>>>(q, tmp, ln_g + (size_t)(l * 2 + 0) * 128,
                                            ln_b + (size_t)(l * 2 + 0) * 128, qb);
        gemm_mfma_k<<<dim3(625, 2), 256, 0, stream>>>(
            qb, Wf1T[l], bf1 + (size_t)l * 128, nullptr, hb, 128, 1);
        gemm_mfma_k<<<dim3(625, 2), 256, 0, stream>>>(
            hb, Wf2T[l], bf2 + (size_t)l * 128, tmp, nullptr, 128, 0);
        add_ln_k<<<10000, 256, 0, stream>>>(q, tmp, ln_g + (size_t)(l * 2 + 1) * 128,
                                            ln_b + (size_t)(l * 2 + 1) * 128, qb);
    }

    // ---- conv head ----
    hipMemsetAsync(pimg, 0, (size_t)206 * 208 * 128 * 2, stream);
    fill_pimg_k<<<2500, 256, 0, stream>>>(qb, pimg);

    conv3_mfma_k<7, 128><<<dim3(400, 2), 256, 0, stream>>>(pimg, w1T, c1f, 128);
    hipMemsetAsync(bnacc, 0, 512 * sizeof(float), stream);
    bn_stats2_k<<<125, 256, 0, stream>>>(c1f, bnacc, 7, 320);
    bn_fin_k<<<1, 128, 0, stream>>>(bnacc, bnmv, 128);
    hipMemsetAsync(c1b, 0, (size_t)206 * 208 * 128 * 2, stream);
    bn_apply_pad_k<<<20000, 256, 0, stream>>>(c1f, bnmv, g1, b1, c1b, 7, 128);

    conv3_mfma_k<3, 128><<<dim3(400, 1), 256, 0, stream>>>(c1b, w2T, c2f, 64);
    hipMemsetAsync(bnacc, 0, 512 * sizeof(float), stream);
    bn_stats2_k<<<125, 256, 0, stream>>>(c2f, bnacc, 6, 320);
    bn_fin_k<<<1, 64, 0, stream>>>(bnacc, bnmv, 64);
    hipMemsetAsync(c2b, 0, (size_t)206 * 208 * 64 * 2, stream);
    bn_apply_pad_k<<<10000, 256, 0, stream>>>(c2f, bnmv, g2, b2, c2b, 6, 64);

    conv3_mfma_k<3, 64><<<dim3(400, 1), 256, 0, stream>>>(c2b, w3T, c3f, 64);
    hipMemsetAsync(bnacc, 0, 512 * sizeof(float), stream);
    bn_stats2_k<<<125, 256, 0, stream>>>(c3f, bnacc, 6, 320);
    bn_fin_k<<<1, 48, 0, stream>>>(bnacc, bnmv, 48);
    hipMemsetAsync(c3b, 0, (size_t)206 * 208 * 64 * 2, stream);
    bn_apply_pad_k<<<10000, 256, 0, stream>>>(c3f, bnmv, g3, b3, c3b, 6, 48);

    conv3_mfma_k<3, 64><<<dim3(400, 1), 256, 0, stream>>>(c3b, w4T, c4f, 64);
    hipMemsetAsync(bnacc, 0, 512 * sizeof(float), stream);
    bn_stats2_k<<<125, 256, 0, stream>>>(c4f, bnacc, 6, 320);
    bn_fin_k<<<1, 48, 0, stream>>>(bnacc, bnmv, 48);
    bn_apply2_k<<<10000, 256, 0, stream>>>(c4f, bnmv, g4, b4, c4b, 6, 48);

    obj_conv_k<<<157, 256, 0, stream>>>(c4b, objw, objb, out);
}